// Round 14
// baseline (201.452 us; speedup 1.0000x reference)
//
#include <hip/hip_runtime.h>
#include <stdint.h>

#define B_    8
#define N_    20000
#define NPTS  (B_*N_)        // 160000
#define G_    10
#define NPIL  100
#define NSB   (B_*NPIL)      // 800 segments
#define BN_EPS 1e-5f

// ---- workspace layout (bytes) ----
#define OFF_COUNTS   0            // 800*4 = 3200
#define OFF_SUMS     3200         // 2400*4 = 9600
#define OFF_STARTS   12800        // 801*4
#define ZERO_BYTES   16320
#define OFF_CENT     19264        // 2400*4
#define OFF_SEG      28864        // 160000*4 (packed seg | rank<<10)
#define OFF_W3BF     668864       // 128*64*2 bf16 [col][k]
#define OFF_W4T      709824       // 768*256*2 bf16 [col][k]
#define OFF_PILW4B   1307840      // 800*768*4 fp32
#define OFF_H3P      3765440      // 160000*128*2 bf16, SORTED rows (upper half hosts h2 temporarily)
#define WS_NEED      44725440

typedef __attribute__((ext_vector_type(8))) short bf16x8;
typedef __attribute__((ext_vector_type(4))) float f32x4;

typedef const __attribute__((address_space(1))) void gas_void;
typedef __attribute__((address_space(3))) void las_void;

__device__ __forceinline__ void gload_lds16(const void* g, void* l){
    __builtin_amdgcn_global_load_lds((gas_void*)g, (las_void*)l, 16, 0, 0);
}

__device__ __forceinline__ int binidx(float v){
    float t = v + 1.0f;
    t = fminf(fmaxf(t, 0.0f), 1.99f);
    return (int)(t / 0.2f);
}
__device__ __forceinline__ unsigned short f2bf(float f){
    unsigned u = __float_as_uint(f);
    u += 0x7fffu + ((u >> 16) & 1u);
    return (unsigned short)(u >> 16);
}
__device__ __forceinline__ unsigned u16max2(unsigned a, unsigned b){
    unsigned ah=a>>16, bh=b>>16, al=a&0xffffu, bl=b&0xffffu;
    return ((ah>bh?ah:bh)<<16) | (al>bl?al:bl);
}
__device__ __forceinline__ uint4 max16(uint4 a, uint4 b){
    uint4 r; r.x=u16max2(a.x,b.x); r.y=u16max2(a.y,b.y);
    r.z=u16max2(a.z,b.z); r.w=u16max2(a.w,b.w); return r;
}

// ---- kA: one batch per block (20000 = 32*625); 100-bin LDS histogram ----
__global__ __launch_bounds__(256) void kA(const float* __restrict__ x,
                                          int* __restrict__ segrank,
                                          int* __restrict__ counts,
                                          float* __restrict__ sums){
    __shared__ int   lc[NPIL];
    __shared__ float lsum[NPIL*3];
    __shared__ int   lbase[NPIL];
    int tid = threadIdx.x;
    if (tid < NPIL){
        lc[tid] = 0;
        lsum[3*tid] = 0.f; lsum[3*tid+1] = 0.f; lsum[3*tid+2] = 0.f;
    }
    __syncthreads();
    int i0  = blockIdx.x * 625;
    int bat = i0 / N_;                      // uniform within block
    int sv[3], lrv[3];
    #pragma unroll
    for (int t = 0; t < 3; t++){
        int ii = tid + t*256;
        int i  = i0 + ii;
        sv[t] = -1;
        if (ii < 625){
            float x0 = x[3*i], x1 = x[3*i+1], x2 = x[3*i+2];
            int s = binidx(x0)*G_ + binidx(x2);
            sv[t] = s;
            lrv[t] = atomicAdd(&lc[s], 1);
            atomicAdd(&lsum[s*3+0], x1);
            atomicAdd(&lsum[s*3+1], x0);
            atomicAdd(&lsum[s*3+2], x2);
        }
    }
    __syncthreads();
    if (tid < NPIL){
        int c = lc[tid];
        if (c > 0){
            int sb = bat*NPIL + tid;
            lbase[tid] = atomicAdd(&counts[sb], c);
            atomicAdd(&sums[3*sb+0], lsum[3*tid+0]);
            atomicAdd(&sums[3*sb+1], lsum[3*tid+1]);
            atomicAdd(&sums[3*sb+2], lsum[3*tid+2]);
        }
    }
    __syncthreads();
    #pragma unroll
    for (int t = 0; t < 3; t++){
        if (sv[t] >= 0){
            int i = i0 + tid + t*256;
            segrank[i] = (bat*NPIL + sv[t]) | ((lbase[sv[t]] + lrv[t]) << 10);
        }
    }
}

// ---- kScan: exclusive prefix sum over 800 counts (1 block) ----
__global__ __launch_bounds__(1024) void kScan(const int* __restrict__ counts,
                                              int* __restrict__ starts){
    __shared__ int s[1024];
    int t = threadIdx.x;
    int c = (t < NSB) ? counts[t] : 0;
    s[t] = c;
    __syncthreads();
    for (int off=1; off<1024; off<<=1){
        int v = (t >= off) ? s[t-off] : 0;
        __syncthreads();
        s[t] += v;
        __syncthreads();
    }
    if (t < NSB) starts[t] = s[t]-c;
    if (t == NSB) starts[NSB] = s[NSB-1];
}

// ---- kB: centroids + W3->bf16 [col][k] + W4T ----
__global__ __launch_bounds__(256) void kB(const int* __restrict__ counts,
                                          const float* __restrict__ sums,
                                          float* __restrict__ cent,
                                          const float* __restrict__ W3,
                                          unsigned short* __restrict__ W3bf,
                                          const float* __restrict__ W4,
                                          unsigned short* __restrict__ W4T){
    int idx = blockIdx.x*256 + threadIdx.x;
    if (idx < 2400){
        cent[idx] = sums[idx] / fmaxf((float)counts[idx/3], 1.0f);
    } else if (idx < 2400 + 8192){
        int t = idx - 2400;
        int col = t >> 6, k = t & 63;     // W3[k][col] -> W3bf[col][k]
        W3bf[t] = f2bf(W3[k*128 + col]);
    } else if (idx < 2400 + 8192 + 196608){
        int t = idx - 2400 - 8192;        // t = k*768 + j (coalesced read)
        int k = t / 768, j = t - k*768;
        W4T[j*256 + k] = f2bf(W4[t]);
    }
}

// ---- kC12: per-point layers 1+2 (fp32 VALU), h2 -> bf16 into UPPER half of h3p row ----
__global__ __launch_bounds__(256) void kC12(const float* __restrict__ x,
                                            const int* __restrict__ segrank,
                                            const int* __restrict__ starts,
                                            const float* __restrict__ cent,
                                            const float* __restrict__ W1,
                                            const float* __restrict__ W2,
                                            unsigned short* __restrict__ h3p){
    int i = blockIdx.x*256 + threadIdx.x;
    if (i >= NPTS) return;
    int pk = segrank[i];
    int sb = pk & 1023;
    int pos = starts[sb] + (pk >> 10);
    float p0 = x[3*i+1], p1 = x[3*i], p2 = x[3*i+2];
    float aug[6];
    aug[0]=p0; aug[1]=p1; aug[2]=p2;
    aug[3]=p0-cent[sb*3+0]; aug[4]=p1-cent[sb*3+1]; aug[5]=p2-cent[sb*3+2];

    float h1[32];
    #pragma unroll
    for (int j=0;j<32;j++){
        float a = 0.f;
        #pragma unroll
        for (int k=0;k<6;k++) a += aug[k]*W1[k*32+j];
        h1[j] = fmaxf(a, 0.f);
    }
    unsigned buf[32];
    #pragma unroll 8
    for (int jp=0;jp<32;jp++){
        float a0 = 0.f, a1 = 0.f;
        #pragma unroll
        for (int k=0;k<32;k++){
            a0 += h1[k]*W2[k*64 + jp*2];
            a1 += h1[k]*W2[k*64 + jp*2 + 1];
        }
        buf[jp] = (unsigned)f2bf(fmaxf(a0,0.f)) | ((unsigned)f2bf(fmaxf(a1,0.f)) << 16);
    }
    uint4* d4 = (uint4*)(h3p + (size_t)pos*128 + 64);
    #pragma unroll
    for (int q=0;q<8;q++) d4[q] = ((const uint4*)buf)[q];
}

// ---- kC3: MFMA GEMM h3[160000,128] = relu(h2[160000,64] @ W3), in place ----
__global__ __launch_bounds__(512) void kC3(const unsigned short* __restrict__ W3bf,
                                           unsigned short* __restrict__ h3p){
    __shared__ unsigned short Al[256*64];
    __shared__ unsigned short Bl[128*64];
    int tid = threadIdx.x;
    int m0  = blockIdx.x * 256;
    #pragma unroll
    for (int it=0; it<4; it++){
        int cc = tid + it*512;
        int row = cc >> 3, ch = cc & 7;
        int chs = ch ^ (row & 7);
        gload_lds16(h3p + (size_t)(m0+row)*128 + 64 + chs*8, (char*)Al + cc*16);
    }
    #pragma unroll
    for (int it=0; it<2; it++){
        int cc = tid + it*512;
        int row = cc >> 3, ch = cc & 7;
        int chs = ch ^ (row & 7);
        gload_lds16(W3bf + (size_t)row*64 + chs*8, (char*)Bl + cc*16);
    }
    __syncthreads();

    int lane = tid & 63, wid = tid >> 6;
    int wm = wid >> 1, wn = wid & 1;
    int l15 = lane & 15, lhi = lane >> 4;

    f32x4 acc[4][4];
    #pragma unroll
    for (int m=0;m<4;m++)
        #pragma unroll
        for (int n=0;n<4;n++) acc[m][n] = (f32x4){0.f,0.f,0.f,0.f};

    #pragma unroll
    for (int kk=0; kk<2; kk++){
        bf16x8 af[4], bfr[4];
        #pragma unroll
        for (int f=0; f<4; f++){
            int ra = wm*64 + f*16 + l15;
            af[f]  = *(const bf16x8*)((char*)Al + ra*128 + (((kk*4+lhi) ^ (ra&7))*16));
            int rb = wn*64 + f*16 + l15;
            bfr[f] = *(const bf16x8*)((char*)Bl + rb*128 + (((kk*4+lhi) ^ (rb&7))*16));
        }
        #pragma unroll
        for (int m=0;m<4;m++)
            #pragma unroll
            for (int n=0;n<4;n++)
                acc[m][n] = __builtin_amdgcn_mfma_f32_16x16x32_bf16(af[m], bfr[n], acc[m][n], 0,0,0);
    }

    #pragma unroll
    for (int m=0;m<4;m++)
        #pragma unroll
        for (int r=0;r<4;r++){
            int row = m0 + wm*64 + m*16 + lhi*4 + r;
            #pragma unroll
            for (int n=0;n<4;n++){
                int col = wn*64 + n*16 + l15;
                h3p[(size_t)row*128 + col] = f2bf(fmaxf(acc[m][n][r], 0.f));
            }
        }
}

// ---- kMB: per-pillar segment-max of h3 + bias = pil.W4hi (kM+kPB fused) ----
__global__ __launch_bounds__(256) void kMB(const unsigned short* __restrict__ h3p,
                                           const int* __restrict__ starts,
                                           const unsigned short* __restrict__ W4T,
                                           float* __restrict__ pilW4b){
    __shared__ uint4 sd[16][16];
    __shared__ unsigned short pill[128];
    int sb = blockIdx.x;
    int tid = threadIdx.x;
    int tx = tid & 15, ty = tid >> 4;
    int s = starts[sb], npts = starts[sb+1] - s;
    uint4 acc = {0u,0u,0u,0u};
    for (int p = ty; p < npts; p += 16){
        uint4 v = *(const uint4*)(h3p + (size_t)(s+p)*128 + tx*8);
        acc = max16(acc, v);
    }
    sd[ty][tx] = acc;
    __syncthreads();
    #pragma unroll
    for (int off=8; off; off>>=1){
        if (ty < off) sd[ty][tx] = max16(sd[ty][tx], sd[ty+off][tx]);
        __syncthreads();
    }
    if (ty == 0) *(uint4*)(pill + tx*8) = sd[0][tx];
    __syncthreads();
    // bias[col] = sum_k pil[k] * W4hi[k][col], fp32 accumulate over bf16
    #pragma unroll
    for (int c=0;c<3;c++){
        int col = tid + c*256;
        const unsigned short* w = W4T + (size_t)col*256 + 128;
        float bsum = 0.f;
        #pragma unroll
        for (int q=0;q<16;q++){
            uint4 wv = *(const uint4*)(w + q*8);
            const unsigned short* wl = (const unsigned short*)&wv;
            #pragma unroll
            for (int e=0;e<8;e++)
                bsum += __uint_as_float(((unsigned)wl[e])<<16)
                      * __uint_as_float(((unsigned)pill[q*8+e])<<16);
        }
        pilW4b[(size_t)sb*768 + col] = bsum;
    }
}

// ---- kD: PERSISTENT blocks (6 nt x 128 groups); B fragments held in registers;
//      per pillar: 64-row A chunks via gload_lds, MFMA K=128, deferred bias+relu ----
__global__ __launch_bounds__(256, 3) void kD(const unsigned short* __restrict__ h3p,
                                             const int* __restrict__ starts,
                                             const float* __restrict__ pilW4b,
                                             const unsigned short* __restrict__ W4T,
                                             float* __restrict__ out){
    __shared__ unsigned short Al[64*128];    // 16KB
    __shared__ float red[2][2][64];
    int nt = blockIdx.x >> 7;                // 0..5
    int g  = blockIdx.x & 127;               // XCD = g%8 for all 6 nt of this group
    int n0 = nt * 128;
    int tid = threadIdx.x;
    int lane = tid & 63, wid = tid >> 6;
    int wm = wid >> 1, wn = wid & 1;
    int l15 = lane & 15, lhi = lane >> 4;

    // B fragments in registers, loaded once: bfr[kk][n]
    bf16x8 bfr[4][4];
    #pragma unroll
    for (int kk=0;kk<4;kk++)
        #pragma unroll
        for (int n=0;n<4;n++){
            int rb = n0 + wn*64 + n*16 + l15;
            bfr[kk][n] = *(const bf16x8*)(W4T + (size_t)rb*256 + (kk*4+lhi)*8);
        }

    // tid-constant A-stage geometry
    int arow[4], achs[4];
    #pragma unroll
    for (int it=0;it<4;it++){
        int cc = tid + it*256;
        arow[it] = cc >> 4;
        achs[it] = (cc & 15) ^ (arow[it] & 15);
    }

    for (int sb = g; sb < NSB; sb += 128){
        int start = starts[sb];
        int npts  = starts[sb+1] - start;
        if (npts == 0){
            if (tid < 128) out[(size_t)sb*768 + n0 + tid] = 0.f;
            continue;
        }
        const unsigned short* asrc[4];
        #pragma unroll
        for (int it=0;it<4;it++)
            asrc[it] = h3p + (size_t)(start+arow[it])*128 + achs[it]*8;

        float mx[2][4][4];
        #pragma unroll
        for (int m=0;m<2;m++)
            #pragma unroll
            for (int n=0;n<4;n++)
                #pragma unroll
                for (int r=0;r<4;r++) mx[m][n][r] = -3.0e38f;

        int nfull = npts >> 6;
        int tailr = npts & 63;

        for (int c=0; c<nfull; c++){
            __syncthreads();
            #pragma unroll
            for (int it=0; it<4; it++){
                gload_lds16(asrc[it], (char*)Al + (tid + it*256)*16);
                asrc[it] += 64*128;
            }
            __syncthreads();
            f32x4 acc[2][4];
            #pragma unroll
            for (int m=0;m<2;m++)
                #pragma unroll
                for (int n=0;n<4;n++) acc[m][n] = (f32x4){0.f,0.f,0.f,0.f};
            #pragma unroll
            for (int kk=0; kk<4; kk++){
                bf16x8 af[2];
                #pragma unroll
                for (int f=0; f<2; f++){
                    int ra = wm*32 + f*16 + l15;
                    af[f] = *(const bf16x8*)((const char*)Al + ra*256 + (((kk*4+lhi) ^ (ra&15))*16));
                }
                #pragma unroll
                for (int m=0;m<2;m++)
                    #pragma unroll
                    for (int n=0;n<4;n++)
                        acc[m][n] = __builtin_amdgcn_mfma_f32_16x16x32_bf16(af[m], bfr[kk][n], acc[m][n], 0,0,0);
            }
            #pragma unroll
            for (int m=0;m<2;m++)
                #pragma unroll
                for (int n=0;n<4;n++)
                    #pragma unroll
                    for (int r=0;r<4;r++)
                        mx[m][n][r] = fmaxf(mx[m][n][r], acc[m][n][r]);
        }
        if (tailr > 0){
            int base = nfull << 6;
            __syncthreads();
            #pragma unroll
            for (int it=0; it<4; it++){
                int idx = start + base + arow[it];
                idx = idx < NPTS ? idx : NPTS-1;   // clamp; excluded by predicate below
                gload_lds16(h3p + (size_t)idx*128 + achs[it]*8, (char*)Al + (tid + it*256)*16);
            }
            __syncthreads();
            f32x4 acc[2][4];
            #pragma unroll
            for (int m=0;m<2;m++)
                #pragma unroll
                for (int n=0;n<4;n++) acc[m][n] = (f32x4){0.f,0.f,0.f,0.f};
            #pragma unroll
            for (int kk=0; kk<4; kk++){
                bf16x8 af[2];
                #pragma unroll
                for (int f=0; f<2; f++){
                    int ra = wm*32 + f*16 + l15;
                    af[f] = *(const bf16x8*)((const char*)Al + ra*256 + (((kk*4+lhi) ^ (ra&15))*16));
                }
                #pragma unroll
                for (int m=0;m<2;m++)
                    #pragma unroll
                    for (int n=0;n<4;n++)
                        acc[m][n] = __builtin_amdgcn_mfma_f32_16x16x32_bf16(af[m], bfr[kk][n], acc[m][n], 0,0,0);
            }
            #pragma unroll
            for (int m=0;m<2;m++)
                #pragma unroll
                for (int r=0;r<4;r++){
                    int p = wm*32 + m*16 + lhi*4 + r;
                    if (p < tailr){
                        #pragma unroll
                        for (int n=0;n<4;n++)
                            mx[m][n][r] = fmaxf(mx[m][n][r], acc[m][n][r]);
                    }
                }
        }

        float red4[4];
        #pragma unroll
        for (int n=0;n<4;n++){
            float v = -3.0e38f;
            #pragma unroll
            for (int m=0;m<2;m++)
                #pragma unroll
                for (int r=0;r<4;r++) v = fmaxf(v, mx[m][n][r]);
            v = fmaxf(v, __shfl_xor(v, 16));
            v = fmaxf(v, __shfl_xor(v, 32));
            red4[n] = v;
        }
        if (lhi == 0){
            #pragma unroll
            for (int n=0;n<4;n++) red[wm][wn][n*16 + l15] = red4[n];
        }
        __syncthreads();
        if (wm == 0){
            float v = fmaxf(red[0][wn][lane], red[1][wn][lane]);
            int col = n0 + wn*64 + lane;
            v = fmaxf(v + pilW4b[(size_t)sb*768 + col], 0.f);
            out[(size_t)sb*768 + col] = v;
        }
    }
}

// ---- kE: per-pillar BatchNorm over (B, 768), in place ----
__global__ __launch_bounds__(256) void kE(float* __restrict__ out,
                                          const float* __restrict__ gamma,
                                          const float* __restrict__ beta){
    int p = blockIdx.x;
    int tid = threadIdx.x;
    float v[B_*3];
    float sum = 0.f, ssq = 0.f;
    #pragma unroll
    for (int b=0;b<B_;b++)
        #pragma unroll
        for (int r=0;r<3;r++){
            float t = out[(b*NPIL + p)*768 + tid + r*256];
            v[b*3+r] = t;
            sum += t; ssq += t*t;
        }
    #pragma unroll
    for (int off=32; off; off>>=1){
        sum += __shfl_xor(sum, off);
        ssq += __shfl_xor(ssq, off);
    }
    __shared__ float ls[8];
    __shared__ float sc[2];
    int lane = tid & 63, w = tid >> 6;
    if (lane == 0){ ls[w] = sum; ls[4+w] = ssq; }
    __syncthreads();
    if (tid == 0){
        float S = ls[0]+ls[1]+ls[2]+ls[3];
        float Q = ls[4]+ls[5]+ls[6]+ls[7];
        float mean = S * (1.0f/6144.0f);
        float var  = Q * (1.0f/6144.0f) - mean*mean;
        float scale = rsqrtf(var + BN_EPS) * gamma[p];
        sc[0] = scale;
        sc[1] = beta[p] - mean*scale;
    }
    __syncthreads();
    float scale = sc[0], shift = sc[1];
    #pragma unroll
    for (int b=0;b<B_;b++)
        #pragma unroll
        for (int r=0;r<3;r++)
            out[(b*NPIL + p)*768 + tid + r*256] = v[b*3+r]*scale + shift;
}

extern "C" void kernel_launch(void* const* d_in, const int* in_sizes, int n_in,
                              void* d_out, int out_size, void* d_ws, size_t ws_size,
                              hipStream_t stream){
    if (ws_size < (size_t)WS_NEED) return;
    const float* x     = (const float*)d_in[0];
    const float* W1    = (const float*)d_in[1];
    const float* W2    = (const float*)d_in[2];
    const float* W3    = (const float*)d_in[3];
    const float* W4    = (const float*)d_in[4];
    const float* gamma = (const float*)d_in[5];
    const float* beta  = (const float*)d_in[6];
    float* out = (float*)d_out;
    char*  ws  = (char*)d_ws;

    int*            counts = (int*)           (ws + OFF_COUNTS);
    float*          sums   = (float*)         (ws + OFF_SUMS);
    int*            starts = (int*)           (ws + OFF_STARTS);
    float*          cent   = (float*)         (ws + OFF_CENT);
    int*            segrank= (int*)           (ws + OFF_SEG);
    unsigned short* W3bf   = (unsigned short*)(ws + OFF_W3BF);
    unsigned short* W4T    = (unsigned short*)(ws + OFF_W4T);
    float*          pilW4b = (float*)         (ws + OFF_PILW4B);
    unsigned short* h3p    = (unsigned short*)(ws + OFF_H3P);

    hipMemsetAsync(d_ws, 0, ZERO_BYTES, stream);

    kA<<<256, 256, 0, stream>>>(x, segrank, counts, sums);
    kScan<<<1, 1024, 0, stream>>>(counts, starts);
    kB<<<(2400+8192+196608+255)/256, 256, 0, stream>>>(counts, sums, cent, W3, W3bf, W4, W4T);
    kC12<<<(NPTS+255)/256, 256, 0, stream>>>(x, segrank, starts, cent, W1, W2, h3p);
    kC3<<<NPTS/256, 512, 0, stream>>>(W3bf, h3p);
    kMB<<<NSB, 256, 0, stream>>>(h3p, starts, W4T, pilW4b);
    kD<<<768, 256, 0, stream>>>(h3p, starts, pilW4b, W4T, out);
    kE<<<NPIL, 256, 0, stream>>>(out, gamma, beta);
}

// Round 15
// 196.944 us; speedup vs baseline: 1.0229x; 1.0229x over previous
//
#include <hip/hip_runtime.h>
#include <stdint.h>

#define B_    8
#define N_    20000
#define NPTS  (B_*N_)        // 160000
#define G_    10
#define NPIL  100
#define NSB   (B_*NPIL)      // 800 segments
#define BN_EPS 1e-5f

// ---- workspace layout (bytes) ----
#define OFF_COUNTS   0            // 800*4 = 3200
#define OFF_SUMS     3200         // 2400*4 = 9600
#define OFF_STARTS   12800        // 801*4
#define ZERO_BYTES   16320
#define OFF_CENT     19264        // 2400*4
#define OFF_SEG      28864        // 160000*4 (packed seg | rank<<10)
#define OFF_W3BF     668864       // 128*64*2 bf16 [col][k]
#define OFF_W4T      709824       // 768*256*2 bf16 [col][k]
#define OFF_PILBF    1103040      // 800*128*2 bf16
#define OFF_PILW4B   1307840      // 800*768*4 fp32
#define OFF_H3P      3765440      // 160000*128*2 bf16, SORTED rows (upper half hosts h2 temporarily)
#define WS_NEED      44725440

typedef __attribute__((ext_vector_type(8))) short bf16x8;
typedef __attribute__((ext_vector_type(4))) float f32x4;

typedef const __attribute__((address_space(1))) void gas_void;
typedef __attribute__((address_space(3))) void las_void;

__device__ __forceinline__ void gload_lds16(const void* g, void* l){
    __builtin_amdgcn_global_load_lds((gas_void*)g, (las_void*)l, 16, 0, 0);
}

__device__ __forceinline__ int binidx(float v){
    float t = v + 1.0f;
    t = fminf(fmaxf(t, 0.0f), 1.99f);
    return (int)(t / 0.2f);
}
__device__ __forceinline__ unsigned short f2bf(float f){
    unsigned u = __float_as_uint(f);
    u += 0x7fffu + ((u >> 16) & 1u);
    return (unsigned short)(u >> 16);
}
__device__ __forceinline__ unsigned u16max2(unsigned a, unsigned b){
    unsigned ah=a>>16, bh=b>>16, al=a&0xffffu, bl=b&0xffffu;
    return ((ah>bh?ah:bh)<<16) | (al>bl?al:bl);
}
__device__ __forceinline__ uint4 max16(uint4 a, uint4 b){
    uint4 r; r.x=u16max2(a.x,b.x); r.y=u16max2(a.y,b.y);
    r.z=u16max2(a.z,b.z); r.w=u16max2(a.w,b.w); return r;
}

// ---- kA: one batch per block (20000 = 32*625); 100-bin LDS histogram ----
__global__ __launch_bounds__(256) void kA(const float* __restrict__ x,
                                          int* __restrict__ segrank,
                                          int* __restrict__ counts,
                                          float* __restrict__ sums){
    __shared__ int   lc[NPIL];
    __shared__ float lsum[NPIL*3];
    __shared__ int   lbase[NPIL];
    int tid = threadIdx.x;
    if (tid < NPIL){
        lc[tid] = 0;
        lsum[3*tid] = 0.f; lsum[3*tid+1] = 0.f; lsum[3*tid+2] = 0.f;
    }
    __syncthreads();
    int i0  = blockIdx.x * 625;
    int bat = i0 / N_;                      // uniform within block
    int sv[3], lrv[3];
    #pragma unroll
    for (int t = 0; t < 3; t++){
        int ii = tid + t*256;
        int i  = i0 + ii;
        sv[t] = -1;
        if (ii < 625){
            float x0 = x[3*i], x1 = x[3*i+1], x2 = x[3*i+2];
            int s = binidx(x0)*G_ + binidx(x2);
            sv[t] = s;
            lrv[t] = atomicAdd(&lc[s], 1);
            atomicAdd(&lsum[s*3+0], x1);
            atomicAdd(&lsum[s*3+1], x0);
            atomicAdd(&lsum[s*3+2], x2);
        }
    }
    __syncthreads();
    if (tid < NPIL){
        int c = lc[tid];
        if (c > 0){
            int sb = bat*NPIL + tid;
            lbase[tid] = atomicAdd(&counts[sb], c);
            atomicAdd(&sums[3*sb+0], lsum[3*tid+0]);
            atomicAdd(&sums[3*sb+1], lsum[3*tid+1]);
            atomicAdd(&sums[3*sb+2], lsum[3*tid+2]);
        }
    }
    __syncthreads();
    #pragma unroll
    for (int t = 0; t < 3; t++){
        if (sv[t] >= 0){
            int i = i0 + tid + t*256;
            segrank[i] = (bat*NPIL + sv[t]) | ((lbase[sv[t]] + lrv[t]) << 10);
        }
    }
}

// ---- kScan: exclusive prefix sum over 800 counts (1 block) ----
__global__ __launch_bounds__(1024) void kScan(const int* __restrict__ counts,
                                              int* __restrict__ starts){
    __shared__ int s[1024];
    int t = threadIdx.x;
    int c = (t < NSB) ? counts[t] : 0;
    s[t] = c;
    __syncthreads();
    for (int off=1; off<1024; off<<=1){
        int v = (t >= off) ? s[t-off] : 0;
        __syncthreads();
        s[t] += v;
        __syncthreads();
    }
    if (t < NSB) starts[t] = s[t]-c;
    if (t == NSB) starts[NSB] = s[NSB-1];
}

// ---- kB: centroids + W3->bf16 [col][k] + W4T ----
__global__ __launch_bounds__(256) void kB(const int* __restrict__ counts,
                                          const float* __restrict__ sums,
                                          float* __restrict__ cent,
                                          const float* __restrict__ W3,
                                          unsigned short* __restrict__ W3bf,
                                          const float* __restrict__ W4,
                                          unsigned short* __restrict__ W4T){
    int idx = blockIdx.x*256 + threadIdx.x;
    if (idx < 2400){
        cent[idx] = sums[idx] / fmaxf((float)counts[idx/3], 1.0f);
    } else if (idx < 2400 + 8192){
        int t = idx - 2400;
        int col = t >> 6, k = t & 63;     // W3[k][col] -> W3bf[col][k]
        W3bf[t] = f2bf(W3[k*128 + col]);
    } else if (idx < 2400 + 8192 + 196608){
        int t = idx - 2400 - 8192;        // t = k*768 + j (coalesced read)
        int k = t / 768, j = t - k*768;
        W4T[j*256 + k] = f2bf(W4[t]);
    }
}

// ---- kC12: per-point layers 1+2 (fp32 VALU), h2 -> bf16 into UPPER half of h3p row ----
__global__ __launch_bounds__(256) void kC12(const float* __restrict__ x,
                                            const int* __restrict__ segrank,
                                            const int* __restrict__ starts,
                                            const float* __restrict__ cent,
                                            const float* __restrict__ W1,
                                            const float* __restrict__ W2,
                                            unsigned short* __restrict__ h3p){
    int i = blockIdx.x*256 + threadIdx.x;
    if (i >= NPTS) return;
    int pk = segrank[i];
    int sb = pk & 1023;
    int pos = starts[sb] + (pk >> 10);
    float p0 = x[3*i+1], p1 = x[3*i], p2 = x[3*i+2];
    float aug[6];
    aug[0]=p0; aug[1]=p1; aug[2]=p2;
    aug[3]=p0-cent[sb*3+0]; aug[4]=p1-cent[sb*3+1]; aug[5]=p2-cent[sb*3+2];

    float h1[32];
    #pragma unroll
    for (int j=0;j<32;j++){
        float a = 0.f;
        #pragma unroll
        for (int k=0;k<6;k++) a += aug[k]*W1[k*32+j];
        h1[j] = fmaxf(a, 0.f);
    }
    unsigned buf[32];
    #pragma unroll 8
    for (int jp=0;jp<32;jp++){
        float a0 = 0.f, a1 = 0.f;
        #pragma unroll
        for (int k=0;k<32;k++){
            a0 += h1[k]*W2[k*64 + jp*2];
            a1 += h1[k]*W2[k*64 + jp*2 + 1];
        }
        buf[jp] = (unsigned)f2bf(fmaxf(a0,0.f)) | ((unsigned)f2bf(fmaxf(a1,0.f)) << 16);
    }
    uint4* d4 = (uint4*)(h3p + (size_t)pos*128 + 64);
    #pragma unroll
    for (int q=0;q<8;q++) d4[q] = ((const uint4*)buf)[q];
}

// ---- kC3: MFMA GEMM h3[160000,128] = relu(h2[160000,64] @ W3), in place ----
__global__ __launch_bounds__(512) void kC3(const unsigned short* __restrict__ W3bf,
                                           unsigned short* __restrict__ h3p){
    __shared__ unsigned short Al[256*64];
    __shared__ unsigned short Bl[128*64];
    int tid = threadIdx.x;
    int m0  = blockIdx.x * 256;
    #pragma unroll
    for (int it=0; it<4; it++){
        int cc = tid + it*512;
        int row = cc >> 3, ch = cc & 7;
        int chs = ch ^ (row & 7);
        gload_lds16(h3p + (size_t)(m0+row)*128 + 64 + chs*8, (char*)Al + cc*16);
    }
    #pragma unroll
    for (int it=0; it<2; it++){
        int cc = tid + it*512;
        int row = cc >> 3, ch = cc & 7;
        int chs = ch ^ (row & 7);
        gload_lds16(W3bf + (size_t)row*64 + chs*8, (char*)Bl + cc*16);
    }
    __syncthreads();

    int lane = tid & 63, wid = tid >> 6;
    int wm = wid >> 1, wn = wid & 1;
    int l15 = lane & 15, lhi = lane >> 4;

    f32x4 acc[4][4];
    #pragma unroll
    for (int m=0;m<4;m++)
        #pragma unroll
        for (int n=0;n<4;n++) acc[m][n] = (f32x4){0.f,0.f,0.f,0.f};

    #pragma unroll
    for (int kk=0; kk<2; kk++){
        bf16x8 af[4], bfr[4];
        #pragma unroll
        for (int f=0; f<4; f++){
            int ra = wm*64 + f*16 + l15;
            af[f]  = *(const bf16x8*)((char*)Al + ra*128 + (((kk*4+lhi) ^ (ra&7))*16));
            int rb = wn*64 + f*16 + l15;
            bfr[f] = *(const bf16x8*)((char*)Bl + rb*128 + (((kk*4+lhi) ^ (rb&7))*16));
        }
        #pragma unroll
        for (int m=0;m<4;m++)
            #pragma unroll
            for (int n=0;n<4;n++)
                acc[m][n] = __builtin_amdgcn_mfma_f32_16x16x32_bf16(af[m], bfr[n], acc[m][n], 0,0,0);
    }

    #pragma unroll
    for (int m=0;m<4;m++)
        #pragma unroll
        for (int r=0;r<4;r++){
            int row = m0 + wm*64 + m*16 + lhi*4 + r;
            #pragma unroll
            for (int n=0;n<4;n++){
                int col = wn*64 + n*16 + l15;
                h3p[(size_t)row*128 + col] = f2bf(fmaxf(acc[m][n][r], 0.f));
            }
        }
}

// ---- kM: per-pillar segment-max of h3 (wide loads, LDS tree) ----
__global__ __launch_bounds__(256) void kM(const unsigned short* __restrict__ h3p,
                                          const int* __restrict__ starts,
                                          unsigned short* __restrict__ pilbf){
    __shared__ uint4 sd[16][16];
    int sb = blockIdx.x;
    int tx = threadIdx.x & 15, ty = threadIdx.x >> 4;
    int s = starts[sb], npts = starts[sb+1] - s;
    uint4 acc = {0u,0u,0u,0u};
    for (int p = ty; p < npts; p += 16){
        uint4 v = *(const uint4*)(h3p + (size_t)(s+p)*128 + tx*8);
        acc = max16(acc, v);
    }
    sd[ty][tx] = acc;
    __syncthreads();
    #pragma unroll
    for (int off=8; off; off>>=1){
        if (ty < off) sd[ty][tx] = max16(sd[ty][tx], sd[ty+off][tx]);
        __syncthreads();
    }
    if (ty == 0) *(uint4*)(pilbf + sb*128 + tx*8) = sd[0][tx];
}

// ---- kPB: MFMA GEMM pilW4b[800,768] = pilbf[800,128] @ W4[128:,:] ----
__global__ __launch_bounds__(256) void kPB(const unsigned short* __restrict__ pilbf,
                                           const unsigned short* __restrict__ W4T,
                                           float* __restrict__ pilW4b){
    __shared__ unsigned short Al[128*128];
    __shared__ unsigned short Bl[128*128];
    int m0 = blockIdx.x * 128;
    int n0 = blockIdx.y * 128;
    int tid = threadIdx.x;
    #pragma unroll
    for (int it=0; it<8; it++){
        int cc = tid + it*256;
        int row = cc >> 4, ch = cc & 15;
        int chs = ch ^ (row & 15);
        uint4 v = {0u,0u,0u,0u};
        if (m0 + row < NSB) v = *(const uint4*)(pilbf + (size_t)(m0+row)*128 + chs*8);
        *(uint4*)((char*)Al + cc*16) = v;
        uint4 vb = *(const uint4*)(W4T + (size_t)(n0+row)*256 + 128 + chs*8);
        *(uint4*)((char*)Bl + cc*16) = vb;
    }
    __syncthreads();
    int lane = tid & 63, wid = tid >> 6;
    int wm = wid >> 1, wn = wid & 1;
    int l15 = lane & 15, lhi = lane >> 4;
    f32x4 acc[4][4];
    #pragma unroll
    for (int m=0;m<4;m++)
        #pragma unroll
        for (int n=0;n<4;n++) acc[m][n] = (f32x4){0.f,0.f,0.f,0.f};
    #pragma unroll
    for (int kk=0; kk<4; kk++){
        bf16x8 af[4], bfr[4];
        #pragma unroll
        for (int f=0; f<4; f++){
            int ra = wm*64 + f*16 + l15;
            af[f]  = *(const bf16x8*)((char*)Al + ra*256 + (((kk*4+lhi) ^ (ra&15))*16));
            int rb = wn*64 + f*16 + l15;
            bfr[f] = *(const bf16x8*)((char*)Bl + rb*256 + (((kk*4+lhi) ^ (rb&15))*16));
        }
        #pragma unroll
        for (int m=0;m<4;m++)
            #pragma unroll
            for (int n=0;n<4;n++)
                acc[m][n] = __builtin_amdgcn_mfma_f32_16x16x32_bf16(af[m], bfr[n], acc[m][n], 0,0,0);
    }
    #pragma unroll
    for (int m=0;m<4;m++)
        #pragma unroll
        for (int r=0;r<4;r++){
            int p = wm*64 + m*16 + lhi*4 + r;
            int sbp = m0 + p;
            if (sbp < NSB){
                #pragma unroll
                for (int n=0;n<4;n++)
                    pilW4b[(size_t)sbp*768 + n0 + wn*64 + n*16 + l15] = acc[m][n][r];
            }
        }
}

// ---- kD: XCD-paired (sb,nt) grid 4800 (as R13); B fragments in REGISTERS loaded
//      once from W4T (no Bl LDS); 64-row A chunks via gload_lds; peeled full/tail;
//      deferred bias+relu at final write. No launch_bounds min -> allocator free. ----
__global__ __launch_bounds__(256) void kD(const unsigned short* __restrict__ h3p,
                                          const int* __restrict__ starts,
                                          const float* __restrict__ pilW4b,
                                          const unsigned short* __restrict__ W4T,
                                          float* __restrict__ out){
    __shared__ unsigned short Al[64*128];    // 16KB
    __shared__ float red[2][2][64];
    int b  = blockIdx.x;
    int x_ = b & 7, t_ = b >> 3;
    int k_ = t_ / 6, nt = t_ - k_*6;
    int sb = x_ + 8*k_;
    int n0 = nt * 128;
    int tid = threadIdx.x;
    int start = starts[sb];
    int npts  = starts[sb+1] - start;
    if (npts == 0){
        if (tid < 128) out[(size_t)sb*768 + n0 + tid] = 0.f;
        return;
    }
    int lane = tid & 63, wid = tid >> 6;
    int wm = wid >> 1, wn = wid & 1;
    int l15 = lane & 15, lhi = lane >> 4;

    // B fragments in registers, loaded once from global (W4T is L2-hot, 393KB)
    bf16x8 bfr[4][4];
    #pragma unroll
    for (int kk=0;kk<4;kk++)
        #pragma unroll
        for (int n=0;n<4;n++){
            int rb = n0 + wn*64 + n*16 + l15;
            bfr[kk][n] = *(const bf16x8*)(W4T + (size_t)rb*256 + (kk*4+lhi)*8);
        }

    // hoisted per-thread A-stage source pointers (advance 64 rows = 16KB per chunk)
    const unsigned short* asrc[4];
    int arow[4], achs[4];
    #pragma unroll
    for (int it=0; it<4; it++){
        int cc = tid + it*256;
        int row = cc >> 4, ch = cc & 15;
        arow[it] = row;
        achs[it] = ch ^ (row & 15);
        asrc[it] = h3p + (size_t)(start+row)*128 + achs[it]*8;
    }

    float mx[2][4][4];
    #pragma unroll
    for (int m=0;m<2;m++)
        #pragma unroll
        for (int n=0;n<4;n++)
            #pragma unroll
            for (int r=0;r<4;r++) mx[m][n][r] = -3.0e38f;

    int nfull = npts >> 6;
    int tailr = npts & 63;

    for (int c=0; c<nfull; c++){
        __syncthreads();
        #pragma unroll
        for (int it=0; it<4; it++){
            gload_lds16(asrc[it], (char*)Al + (tid + it*256)*16);
            asrc[it] += 64*128;
        }
        __syncthreads();
        f32x4 acc[2][4];
        #pragma unroll
        for (int m=0;m<2;m++)
            #pragma unroll
            for (int n=0;n<4;n++) acc[m][n] = (f32x4){0.f,0.f,0.f,0.f};
        #pragma unroll
        for (int kk=0; kk<4; kk++){
            bf16x8 af[2];
            #pragma unroll
            for (int f=0; f<2; f++){
                int ra = wm*32 + f*16 + l15;
                af[f] = *(const bf16x8*)((const char*)Al + ra*256 + (((kk*4+lhi) ^ (ra&15))*16));
            }
            #pragma unroll
            for (int m=0;m<2;m++)
                #pragma unroll
                for (int n=0;n<4;n++)
                    acc[m][n] = __builtin_amdgcn_mfma_f32_16x16x32_bf16(af[m], bfr[kk][n], acc[m][n], 0,0,0);
        }
        #pragma unroll
        for (int m=0;m<2;m++)
            #pragma unroll
            for (int n=0;n<4;n++)
                #pragma unroll
                for (int r=0;r<4;r++)
                    mx[m][n][r] = fmaxf(mx[m][n][r], acc[m][n][r]);
    }
    if (tailr > 0){
        int base = nfull << 6;
        __syncthreads();
        #pragma unroll
        for (int it=0; it<4; it++){
            int idx = start + base + arow[it];
            idx = idx < NPTS ? idx : NPTS-1;   // clamp; excluded by predicate below
            gload_lds16(h3p + (size_t)idx*128 + achs[it]*8, (char*)Al + (tid + it*256)*16);
        }
        __syncthreads();
        f32x4 acc[2][4];
        #pragma unroll
        for (int m=0;m<2;m++)
            #pragma unroll
            for (int n=0;n<4;n++) acc[m][n] = (f32x4){0.f,0.f,0.f,0.f};
        #pragma unroll
        for (int kk=0; kk<4; kk++){
            bf16x8 af[2];
            #pragma unroll
            for (int f=0; f<2; f++){
                int ra = wm*32 + f*16 + l15;
                af[f] = *(const bf16x8*)((const char*)Al + ra*256 + (((kk*4+lhi) ^ (ra&15))*16));
            }
            #pragma unroll
            for (int m=0;m<2;m++)
                #pragma unroll
                for (int n=0;n<4;n++)
                    acc[m][n] = __builtin_amdgcn_mfma_f32_16x16x32_bf16(af[m], bfr[kk][n], acc[m][n], 0,0,0);
        }
        #pragma unroll
        for (int m=0;m<2;m++)
            #pragma unroll
            for (int r=0;r<4;r++){
                int p = wm*32 + m*16 + lhi*4 + r;
                if (p < tailr){
                    #pragma unroll
                    for (int n=0;n<4;n++)
                        mx[m][n][r] = fmaxf(mx[m][n][r], acc[m][n][r]);
                }
            }
    }

    float red4[4];
    #pragma unroll
    for (int n=0;n<4;n++){
        float v = -3.0e38f;
        #pragma unroll
        for (int m=0;m<2;m++)
            #pragma unroll
            for (int r=0;r<4;r++) v = fmaxf(v, mx[m][n][r]);
        v = fmaxf(v, __shfl_xor(v, 16));
        v = fmaxf(v, __shfl_xor(v, 32));
        red4[n] = v;
    }
    if (lhi == 0){
        #pragma unroll
        for (int n=0;n<4;n++) red[wm][wn][n*16 + l15] = red4[n];
    }
    __syncthreads();
    if (wm == 0){
        float v = fmaxf(red[0][wn][lane], red[1][wn][lane]);
        int col = n0 + wn*64 + lane;
        v = fmaxf(v + pilW4b[(size_t)sb*768 + col], 0.f);
        out[(size_t)sb*768 + col] = v;
    }
}

// ---- kE: per-pillar BatchNorm over (B, 768), in place ----
__global__ __launch_bounds__(256) void kE(float* __restrict__ out,
                                          const float* __restrict__ gamma,
                                          const float* __restrict__ beta){
    int p = blockIdx.x;
    int tid = threadIdx.x;
    float v[B_*3];
    float sum = 0.f, ssq = 0.f;
    #pragma unroll
    for (int b=0;b<B_;b++)
        #pragma unroll
        for (int r=0;r<3;r++){
            float t = out[(b*NPIL + p)*768 + tid + r*256];
            v[b*3+r] = t;
            sum += t; ssq += t*t;
        }
    #pragma unroll
    for (int off=32; off; off>>=1){
        sum += __shfl_xor(sum, off);
        ssq += __shfl_xor(ssq, off);
    }
    __shared__ float ls[8];
    __shared__ float sc[2];
    int lane = tid & 63, w = tid >> 6;
    if (lane == 0){ ls[w] = sum; ls[4+w] = ssq; }
    __syncthreads();
    if (tid == 0){
        float S = ls[0]+ls[1]+ls[2]+ls[3];
        float Q = ls[4]+ls[5]+ls[6]+ls[7];
        float mean = S * (1.0f/6144.0f);
        float var  = Q * (1.0f/6144.0f) - mean*mean;
        float scale = rsqrtf(var + BN_EPS) * gamma[p];
        sc[0] = scale;
        sc[1] = beta[p] - mean*scale;
    }
    __syncthreads();
    float scale = sc[0], shift = sc[1];
    #pragma unroll
    for (int b=0;b<B_;b++)
        #pragma unroll
        for (int r=0;r<3;r++)
            out[(b*NPIL + p)*768 + tid + r*256] = v[b*3+r]*scale + shift;
}

extern "C" void kernel_launch(void* const* d_in, const int* in_sizes, int n_in,
                              void* d_out, int out_size, void* d_ws, size_t ws_size,
                              hipStream_t stream){
    if (ws_size < (size_t)WS_NEED) return;
    const float* x     = (const float*)d_in[0];
    const float* W1    = (const float*)d_in[1];
    const float* W2    = (const float*)d_in[2];
    const float* W3    = (const float*)d_in[3];
    const float* W4    = (const float*)d_in[4];
    const float* gamma = (const float*)d_in[5];
    const float* beta  = (const float*)d_in[6];
    float* out = (float*)d_out;
    char*  ws  = (char*)d_ws;

    int*            counts = (int*)           (ws + OFF_COUNTS);
    float*          sums   = (float*)         (ws + OFF_SUMS);
    int*            starts = (int*)           (ws + OFF_STARTS);
    float*          cent   = (float*)         (ws + OFF_CENT);
    int*            segrank= (int*)           (ws + OFF_SEG);
    unsigned short* W3bf   = (unsigned short*)(ws + OFF_W3BF);
    unsigned short* W4T    = (unsigned short*)(ws + OFF_W4T);
    unsigned short* pilbf  = (unsigned short*)(ws + OFF_PILBF);
    float*          pilW4b = (float*)         (ws + OFF_PILW4B);
    unsigned short* h3p    = (unsigned short*)(ws + OFF_H3P);

    hipMemsetAsync(d_ws, 0, ZERO_BYTES, stream);

    kA<<<256, 256, 0, stream>>>(x, segrank, counts, sums);
    kScan<<<1, 1024, 0, stream>>>(counts, starts);
    kB<<<(2400+8192+196608+255)/256, 256, 0, stream>>>(counts, sums, cent, W3, W3bf, W4, W4T);
    kC12<<<(NPTS+255)/256, 256, 0, stream>>>(x, segrank, starts, cent, W1, W2, h3p);
    kC3<<<NPTS/256, 512, 0, stream>>>(W3bf, h3p);
    kM<<<NSB, 256, 0, stream>>>(h3p, starts, pilbf);
    dim3 gPB((NSB+127)/128, 6);
    kPB<<<gPB, 256, 0, stream>>>(pilbf, W4T, pilW4b);
    kD<<<4800, 256, 0, stream>>>(h3p, starts, pilW4b, W4T, out);
    kE<<<NPIL, 256, 0, stream>>>(out, gamma, beta);
}

// Round 16
// 182.297 us; speedup vs baseline: 1.1051x; 1.0804x over previous
//
#include <hip/hip_runtime.h>
#include <stdint.h>

#define B_    8
#define N_    20000
#define NPTS  (B_*N_)        // 160000
#define G_    10
#define NPIL  100
#define NSB   (B_*NPIL)      // 800 segments
#define BN_EPS 1e-5f

// ---- workspace layout (bytes) ----
#define OFF_COUNTS   0            // 800*4 = 3200
#define OFF_SUMS     3200         // 2400*4 = 9600
#define OFF_STARTS   12800        // 801*4
#define ZERO_BYTES   16320
#define OFF_CENT     19264        // 2400*4
#define OFF_SEG      28864        // 160000*4 (packed seg | rank<<10)
#define OFF_W3BF     668864       // 128*64*2 bf16 [col][k]
#define OFF_W4T      709824       // 768*256*2 bf16 [col][k]
#define OFF_PILW4B   1307840      // 800*768*4 fp32
#define OFF_H3P      3765440      // 160000*128*2 bf16, SORTED rows (upper half hosts h2 temporarily)
#define WS_NEED      44725440

typedef __attribute__((ext_vector_type(8))) short bf16x8;
typedef __attribute__((ext_vector_type(4))) float f32x4;

typedef const __attribute__((address_space(1))) void gas_void;
typedef __attribute__((address_space(3))) void las_void;

__device__ __forceinline__ void gload_lds16(const void* g, void* l){
    __builtin_amdgcn_global_load_lds((gas_void*)g, (las_void*)l, 16, 0, 0);
}

__device__ __forceinline__ int binidx(float v){
    float t = v + 1.0f;
    t = fminf(fmaxf(t, 0.0f), 1.99f);
    return (int)(t / 0.2f);
}
__device__ __forceinline__ unsigned short f2bf(float f){
    unsigned u = __float_as_uint(f);
    u += 0x7fffu + ((u >> 16) & 1u);
    return (unsigned short)(u >> 16);
}
__device__ __forceinline__ unsigned u16max2(unsigned a, unsigned b){
    unsigned ah=a>>16, bh=b>>16, al=a&0xffffu, bl=b&0xffffu;
    return ((ah>bh?ah:bh)<<16) | (al>bl?al:bl);
}
__device__ __forceinline__ uint4 max16(uint4 a, uint4 b){
    uint4 r; r.x=u16max2(a.x,b.x); r.y=u16max2(a.y,b.y);
    r.z=u16max2(a.z,b.z); r.w=u16max2(a.w,b.w); return r;
}

// ---- kA: blocks 0..255 = per-batch histogram (pillar id + rank, LDS-aggregated);
//      blocks 256..1055 = W3/W4 transposes (independent work, overlapped) ----
__global__ __launch_bounds__(256) void kA(const float* __restrict__ x,
                                          int* __restrict__ segrank,
                                          int* __restrict__ counts,
                                          float* __restrict__ sums,
                                          const float* __restrict__ W3,
                                          unsigned short* __restrict__ W3bf,
                                          const float* __restrict__ W4,
                                          unsigned short* __restrict__ W4T){
    int blk = blockIdx.x;
    int tid = threadIdx.x;
    if (blk >= 256){
        int idx = (blk-256)*256 + tid;        // 0..204799
        if (idx < 8192){
            int col = idx >> 6, k = idx & 63; // W3[k][col] -> W3bf[col][k]
            W3bf[idx] = f2bf(W3[k*128 + col]);
        } else {
            int t = idx - 8192;               // t = k*768 + j (coalesced read)
            int k = t / 768, j = t - k*768;
            W4T[j*256 + k] = f2bf(W4[t]);
        }
        return;
    }
    __shared__ int   lc[NPIL];
    __shared__ float lsum[NPIL*3];
    __shared__ int   lbase[NPIL];
    if (tid < NPIL){
        lc[tid] = 0;
        lsum[3*tid] = 0.f; lsum[3*tid+1] = 0.f; lsum[3*tid+2] = 0.f;
    }
    __syncthreads();
    int i0  = blk * 625;
    int bat = i0 / N_;                        // uniform within block
    int sv[3], lrv[3];
    #pragma unroll
    for (int t = 0; t < 3; t++){
        int ii = tid + t*256;
        int i  = i0 + ii;
        sv[t] = -1;
        if (ii < 625){
            float x0 = x[3*i], x1 = x[3*i+1], x2 = x[3*i+2];
            int s = binidx(x0)*G_ + binidx(x2);
            sv[t] = s;
            lrv[t] = atomicAdd(&lc[s], 1);
            atomicAdd(&lsum[s*3+0], x1);
            atomicAdd(&lsum[s*3+1], x0);
            atomicAdd(&lsum[s*3+2], x2);
        }
    }
    __syncthreads();
    if (tid < NPIL){
        int c = lc[tid];
        if (c > 0){
            int sb = bat*NPIL + tid;
            lbase[tid] = atomicAdd(&counts[sb], c);
            atomicAdd(&sums[3*sb+0], lsum[3*tid+0]);
            atomicAdd(&sums[3*sb+1], lsum[3*tid+1]);
            atomicAdd(&sums[3*sb+2], lsum[3*tid+2]);
        }
    }
    __syncthreads();
    #pragma unroll
    for (int t = 0; t < 3; t++){
        if (sv[t] >= 0){
            int i = i0 + tid + t*256;
            segrank[i] = (bat*NPIL + sv[t]) | ((lbase[sv[t]] + lrv[t]) << 10);
        }
    }
}

// ---- kScan: exclusive prefix sum over 800 counts + centroids (1 block) ----
__global__ __launch_bounds__(1024) void kScan(const int* __restrict__ counts,
                                              const float* __restrict__ sums,
                                              int* __restrict__ starts,
                                              float* __restrict__ cent){
    __shared__ int s[1024];
    int t = threadIdx.x;
    int c = (t < NSB) ? counts[t] : 0;
    s[t] = c;
    __syncthreads();
    for (int off=1; off<1024; off<<=1){
        int v = (t >= off) ? s[t-off] : 0;
        __syncthreads();
        s[t] += v;
        __syncthreads();
    }
    if (t < NSB) starts[t] = s[t]-c;
    if (t == NSB) starts[NSB] = s[NSB-1];
    for (int idx = t; idx < 2400; idx += 1024)
        cent[idx] = sums[idx] / fmaxf((float)counts[idx/3], 1.0f);
}

// ---- kC12: per-point layers 1+2 (fp32 VALU), h2 -> bf16 into UPPER half of h3p row ----
__global__ __launch_bounds__(256) void kC12(const float* __restrict__ x,
                                            const int* __restrict__ segrank,
                                            const int* __restrict__ starts,
                                            const float* __restrict__ cent,
                                            const float* __restrict__ W1,
                                            const float* __restrict__ W2,
                                            unsigned short* __restrict__ h3p){
    int i = blockIdx.x*256 + threadIdx.x;
    if (i >= NPTS) return;
    int pk = segrank[i];
    int sb = pk & 1023;
    int pos = starts[sb] + (pk >> 10);
    float p0 = x[3*i+1], p1 = x[3*i], p2 = x[3*i+2];
    float aug[6];
    aug[0]=p0; aug[1]=p1; aug[2]=p2;
    aug[3]=p0-cent[sb*3+0]; aug[4]=p1-cent[sb*3+1]; aug[5]=p2-cent[sb*3+2];

    float h1[32];
    #pragma unroll
    for (int j=0;j<32;j++){
        float a = 0.f;
        #pragma unroll
        for (int k=0;k<6;k++) a += aug[k]*W1[k*32+j];
        h1[j] = fmaxf(a, 0.f);
    }
    unsigned buf[32];
    #pragma unroll 8
    for (int jp=0;jp<32;jp++){
        float a0 = 0.f, a1 = 0.f;
        #pragma unroll
        for (int k=0;k<32;k++){
            a0 += h1[k]*W2[k*64 + jp*2];
            a1 += h1[k]*W2[k*64 + jp*2 + 1];
        }
        buf[jp] = (unsigned)f2bf(fmaxf(a0,0.f)) | ((unsigned)f2bf(fmaxf(a1,0.f)) << 16);
    }
    uint4* d4 = (uint4*)(h3p + (size_t)pos*128 + 64);
    #pragma unroll
    for (int q=0;q<8;q++) d4[q] = ((const uint4*)buf)[q];
}

// ---- kC3: MFMA GEMM h3[160000,128] = relu(h2[160000,64] @ W3), in place ----
__global__ __launch_bounds__(512) void kC3(const unsigned short* __restrict__ W3bf,
                                           unsigned short* __restrict__ h3p){
    __shared__ unsigned short Al[256*64];
    __shared__ unsigned short Bl[128*64];
    int tid = threadIdx.x;
    int m0  = blockIdx.x * 256;
    #pragma unroll
    for (int it=0; it<4; it++){
        int cc = tid + it*512;
        int row = cc >> 3, ch = cc & 7;
        int chs = ch ^ (row & 7);
        gload_lds16(h3p + (size_t)(m0+row)*128 + 64 + chs*8, (char*)Al + cc*16);
    }
    #pragma unroll
    for (int it=0; it<2; it++){
        int cc = tid + it*512;
        int row = cc >> 3, ch = cc & 7;
        int chs = ch ^ (row & 7);
        gload_lds16(W3bf + (size_t)row*64 + chs*8, (char*)Bl + cc*16);
    }
    __syncthreads();

    int lane = tid & 63, wid = tid >> 6;
    int wm = wid >> 1, wn = wid & 1;
    int l15 = lane & 15, lhi = lane >> 4;

    f32x4 acc[4][4];
    #pragma unroll
    for (int m=0;m<4;m++)
        #pragma unroll
        for (int n=0;n<4;n++) acc[m][n] = (f32x4){0.f,0.f,0.f,0.f};

    #pragma unroll
    for (int kk=0; kk<2; kk++){
        bf16x8 af[4], bfr[4];
        #pragma unroll
        for (int f=0; f<4; f++){
            int ra = wm*64 + f*16 + l15;
            af[f]  = *(const bf16x8*)((char*)Al + ra*128 + (((kk*4+lhi) ^ (ra&7))*16));
            int rb = wn*64 + f*16 + l15;
            bfr[f] = *(const bf16x8*)((char*)Bl + rb*128 + (((kk*4+lhi) ^ (rb&7))*16));
        }
        #pragma unroll
        for (int m=0;m<4;m++)
            #pragma unroll
            for (int n=0;n<4;n++)
                acc[m][n] = __builtin_amdgcn_mfma_f32_16x16x32_bf16(af[m], bfr[n], acc[m][n], 0,0,0);
    }

    #pragma unroll
    for (int m=0;m<4;m++)
        #pragma unroll
        for (int r=0;r<4;r++){
            int row = m0 + wm*64 + m*16 + lhi*4 + r;
            #pragma unroll
            for (int n=0;n<4;n++){
                int col = wn*64 + n*16 + l15;
                h3p[(size_t)row*128 + col] = f2bf(fmaxf(acc[m][n][r], 0.f));
            }
        }
}

// ---- kMB: per-pillar segment-max of h3 + bias = pil.W4hi (kM+kPB fused) ----
__global__ __launch_bounds__(256) void kMB(const unsigned short* __restrict__ h3p,
                                           const int* __restrict__ starts,
                                           const unsigned short* __restrict__ W4T,
                                           float* __restrict__ pilW4b){
    __shared__ uint4 sd[16][16];
    __shared__ unsigned short pill[128];
    int sb = blockIdx.x;
    int tid = threadIdx.x;
    int tx = tid & 15, ty = tid >> 4;
    int s = starts[sb], npts = starts[sb+1] - s;
    uint4 acc = {0u,0u,0u,0u};
    for (int p = ty; p < npts; p += 16){
        uint4 v = *(const uint4*)(h3p + (size_t)(s+p)*128 + tx*8);
        acc = max16(acc, v);
    }
    sd[ty][tx] = acc;
    __syncthreads();
    #pragma unroll
    for (int off=8; off; off>>=1){
        if (ty < off) sd[ty][tx] = max16(sd[ty][tx], sd[ty+off][tx]);
        __syncthreads();
    }
    if (ty == 0) *(uint4*)(pill + tx*8) = sd[0][tx];
    __syncthreads();
    // bias[col] = sum_k pil[k] * W4hi[k][col], fp32 accumulate over bf16
    #pragma unroll
    for (int c=0;c<3;c++){
        int col = tid + c*256;
        const unsigned short* w = W4T + (size_t)col*256 + 128;
        float bsum = 0.f;
        #pragma unroll
        for (int q=0;q<16;q++){
            uint4 wv = *(const uint4*)(w + q*8);
            const unsigned short* wl = (const unsigned short*)&wv;
            #pragma unroll
            for (int e=0;e<8;e++)
                bsum += __uint_as_float(((unsigned)wl[e])<<16)
                      * __uint_as_float(((unsigned)pill[q*8+e])<<16);
        }
        pilW4b[(size_t)sb*768 + col] = bsum;
    }
}

// ---- kD: R13 version (best measured). XCD-paired (sb,nt); async gload_lds;
//      64-row chunks; peeled full/tail; deferred bias+relu at final write ----
__global__ __launch_bounds__(256) void kD(const unsigned short* __restrict__ h3p,
                                          const int* __restrict__ starts,
                                          const float* __restrict__ pilW4b,
                                          const unsigned short* __restrict__ W4T,
                                          float* __restrict__ out){
    __shared__ unsigned short Al[64*128];    // 16KB
    __shared__ unsigned short Bl[128*128];   // 32KB
    __shared__ float red[2][2][64];
    int b  = blockIdx.x;
    int x_ = b & 7, t_ = b >> 3;
    int k_ = t_ / 6, nt = t_ - k_*6;
    int sb = x_ + 8*k_;
    int n0 = nt * 128;
    int tid = threadIdx.x;
    int start = starts[sb];
    int npts  = starts[sb+1] - start;
    if (npts == 0){
        if (tid < 128) out[(size_t)sb*768 + n0 + tid] = 0.f;
        return;
    }
    // stage B async (in flight until first barrier)
    #pragma unroll
    for (int it=0; it<8; it++){
        int cc = tid + it*256;
        int row = cc >> 4, ch = cc & 15;
        int chs = ch ^ (row & 15);
        gload_lds16(W4T + (size_t)(n0+row)*256 + chs*8, (char*)Bl + cc*16);
    }
    // hoisted per-thread A-stage source pointers (advance 64 rows = 16KB per chunk)
    const unsigned short* asrc[4];
    int arow[4], achs[4];
    #pragma unroll
    for (int it=0; it<4; it++){
        int cc = tid + it*256;
        int row = cc >> 4, ch = cc & 15;
        arow[it] = row;
        achs[it] = ch ^ (row & 15);
        asrc[it] = h3p + (size_t)(start+row)*128 + achs[it]*8;
    }
    int lane = tid & 63, wid = tid >> 6;
    int wm = wid >> 1, wn = wid & 1;
    int l15 = lane & 15, lhi = lane >> 4;

    float mx[2][4][4];
    #pragma unroll
    for (int m=0;m<2;m++)
        #pragma unroll
        for (int n=0;n<4;n++)
            #pragma unroll
            for (int r=0;r<4;r++) mx[m][n][r] = -3.0e38f;

    int nfull = npts >> 6;
    int tailr = npts & 63;

    for (int c=0; c<nfull; c++){
        __syncthreads();
        #pragma unroll
        for (int it=0; it<4; it++){
            gload_lds16(asrc[it], (char*)Al + (tid + it*256)*16);
            asrc[it] += 64*128;
        }
        __syncthreads();
        f32x4 acc[2][4];
        #pragma unroll
        for (int m=0;m<2;m++)
            #pragma unroll
            for (int n=0;n<4;n++) acc[m][n] = (f32x4){0.f,0.f,0.f,0.f};
        #pragma unroll
        for (int kk=0; kk<4; kk++){
            bf16x8 af[2], bfr[4];
            #pragma unroll
            for (int f=0; f<2; f++){
                int ra = wm*32 + f*16 + l15;
                af[f] = *(const bf16x8*)((const char*)Al + ra*256 + (((kk*4+lhi) ^ (ra&15))*16));
            }
            #pragma unroll
            for (int f=0; f<4; f++){
                int rb = wn*64 + f*16 + l15;
                bfr[f] = *(const bf16x8*)((const char*)Bl + rb*256 + (((kk*4+lhi) ^ (rb&15))*16));
            }
            #pragma unroll
            for (int m=0;m<2;m++)
                #pragma unroll
                for (int n=0;n<4;n++)
                    acc[m][n] = __builtin_amdgcn_mfma_f32_16x16x32_bf16(af[m], bfr[n], acc[m][n], 0,0,0);
        }
        #pragma unroll
        for (int m=0;m<2;m++)
            #pragma unroll
            for (int n=0;n<4;n++)
                #pragma unroll
                for (int r=0;r<4;r++)
                    mx[m][n][r] = fmaxf(mx[m][n][r], acc[m][n][r]);
    }
    if (tailr > 0){
        int base = nfull << 6;
        __syncthreads();
        #pragma unroll
        for (int it=0; it<4; it++){
            int idx = start + base + arow[it];
            idx = idx < NPTS ? idx : NPTS-1;   // clamp; excluded by predicate below
            gload_lds16(h3p + (size_t)idx*128 + achs[it]*8, (char*)Al + (tid + it*256)*16);
        }
        __syncthreads();
        f32x4 acc[2][4];
        #pragma unroll
        for (int m=0;m<2;m++)
            #pragma unroll
            for (int n=0;n<4;n++) acc[m][n] = (f32x4){0.f,0.f,0.f,0.f};
        #pragma unroll
        for (int kk=0; kk<4; kk++){
            bf16x8 af[2], bfr[4];
            #pragma unroll
            for (int f=0; f<2; f++){
                int ra = wm*32 + f*16 + l15;
                af[f] = *(const bf16x8*)((const char*)Al + ra*256 + (((kk*4+lhi) ^ (ra&15))*16));
            }
            #pragma unroll
            for (int f=0; f<4; f++){
                int rb = wn*64 + f*16 + l15;
                bfr[f] = *(const bf16x8*)((const char*)Bl + rb*256 + (((kk*4+lhi) ^ (rb&15))*16));
            }
            #pragma unroll
            for (int m=0;m<2;m++)
                #pragma unroll
                for (int n=0;n<4;n++)
                    acc[m][n] = __builtin_amdgcn_mfma_f32_16x16x32_bf16(af[m], bfr[n], acc[m][n], 0,0,0);
        }
        #pragma unroll
        for (int m=0;m<2;m++)
            #pragma unroll
            for (int r=0;r<4;r++){
                int p = wm*32 + m*16 + lhi*4 + r;
                if (p < tailr){
                    #pragma unroll
                    for (int n=0;n<4;n++)
                        mx[m][n][r] = fmaxf(mx[m][n][r], acc[m][n][r]);
                }
            }
    }

    float red4[4];
    #pragma unroll
    for (int n=0;n<4;n++){
        float v = -3.0e38f;
        #pragma unroll
        for (int m=0;m<2;m++)
            #pragma unroll
            for (int r=0;r<4;r++) v = fmaxf(v, mx[m][n][r]);
        v = fmaxf(v, __shfl_xor(v, 16));
        v = fmaxf(v, __shfl_xor(v, 32));
        red4[n] = v;
    }
    if (lhi == 0){
        #pragma unroll
        for (int n=0;n<4;n++) red[wm][wn][n*16 + l15] = red4[n];
    }
    __syncthreads();
    if (wm == 0){
        float v = fmaxf(red[0][wn][lane], red[1][wn][lane]);
        int col = n0 + wn*64 + lane;
        v = fmaxf(v + pilW4b[(size_t)sb*768 + col], 0.f);
        out[(size_t)sb*768 + col] = v;
    }
}

// ---- kE: per-pillar BatchNorm over (B, 768), in place ----
__global__ __launch_bounds__(256) void kE(float* __restrict__ out,
                                          const float* __restrict__ gamma,
                                          const float* __restrict__ beta){
    int p = blockIdx.x;
    int tid = threadIdx.x;
    float v[B_*3];
    float sum = 0.f, ssq = 0.f;
    #pragma unroll
    for (int b=0;b<B_;b++)
        #pragma unroll
        for (int r=0;r<3;r++){
            float t = out[(b*NPIL + p)*768 + tid + r*256];
            v[b*3+r] = t;
            sum += t; ssq += t*t;
        }
    #pragma unroll
    for (int off=32; off; off>>=1){
        sum += __shfl_xor(sum, off);
        ssq += __shfl_xor(ssq, off);
    }
    __shared__ float ls[8];
    __shared__ float sc[2];
    int lane = tid & 63, w = tid >> 6;
    if (lane == 0){ ls[w] = sum; ls[4+w] = ssq; }
    __syncthreads();
    if (tid == 0){
        float S = ls[0]+ls[1]+ls[2]+ls[3];
        float Q = ls[4]+ls[5]+ls[6]+ls[7];
        float mean = S * (1.0f/6144.0f);
        float var  = Q * (1.0f/6144.0f) - mean*mean;
        float scale = rsqrtf(var + BN_EPS) * gamma[p];
        sc[0] = scale;
        sc[1] = beta[p] - mean*scale;
    }
    __syncthreads();
    float scale = sc[0], shift = sc[1];
    #pragma unroll
    for (int b=0;b<B_;b++)
        #pragma unroll
        for (int r=0;r<3;r++)
            out[(b*NPIL + p)*768 + tid + r*256] = v[b*3+r]*scale + shift;
}

extern "C" void kernel_launch(void* const* d_in, const int* in_sizes, int n_in,
                              void* d_out, int out_size, void* d_ws, size_t ws_size,
                              hipStream_t stream){
    if (ws_size < (size_t)WS_NEED) return;
    const float* x     = (const float*)d_in[0];
    const float* W1    = (const float*)d_in[1];
    const float* W2    = (const float*)d_in[2];
    const float* W3    = (const float*)d_in[3];
    const float* W4    = (const float*)d_in[4];
    const float* gamma = (const float*)d_in[5];
    const float* beta  = (const float*)d_in[6];
    float* out = (float*)d_out;
    char*  ws  = (char*)d_ws;

    int*            counts = (int*)           (ws + OFF_COUNTS);
    float*          sums   = (float*)         (ws + OFF_SUMS);
    int*            starts = (int*)           (ws + OFF_STARTS);
    float*          cent   = (float*)         (ws + OFF_CENT);
    int*            segrank= (int*)           (ws + OFF_SEG);
    unsigned short* W3bf   = (unsigned short*)(ws + OFF_W3BF);
    unsigned short* W4T    = (unsigned short*)(ws + OFF_W4T);
    float*          pilW4b = (float*)         (ws + OFF_PILW4B);
    unsigned short* h3p    = (unsigned short*)(ws + OFF_H3P);

    hipMemsetAsync(d_ws, 0, ZERO_BYTES, stream);

    kA<<<1056, 256, 0, stream>>>(x, segrank, counts, sums, W3, W3bf, W4, W4T);
    kScan<<<1, 1024, 0, stream>>>(counts, sums, starts, cent);
    kC12<<<(NPTS+255)/256, 256, 0, stream>>>(x, segrank, starts, cent, W1, W2, h3p);
    kC3<<<NPTS/256, 512, 0, stream>>>(W3bf, h3p);
    kMB<<<NSB, 256, 0, stream>>>(h3p, starts, W4T, pilW4b);
    kD<<<4800, 256, 0, stream>>>(h3p, starts, pilW4b, W4T, out);
    kE<<<NPIL, 256, 0, stream>>>(out, gamma, beta);
}

// Round 17
// 175.947 us; speedup vs baseline: 1.1450x; 1.0361x over previous
//
#include <hip/hip_runtime.h>
#include <stdint.h>

#define B_    8
#define N_    20000
#define NPTS  (B_*N_)        // 160000
#define G_    10
#define NPIL  100
#define NSB   (B_*NPIL)      // 800 segments
#define BN_EPS 1e-5f

// ---- workspace layout (bytes) ----
#define OFF_COUNTS   0            // 800*4 = 3200
#define OFF_SUMS     3200         // 2400*4 = 9600
#define OFF_STARTS   12800        // 801*4
#define ZERO_BYTES   16320
#define OFF_CENT     19264        // 2400*4
#define OFF_SEG      28864        // 160000*4 (packed seg | rank<<10)
#define OFF_W3BF     668864       // 128*64*2 bf16 [col][k]
#define OFF_W4T      709824       // 768*256*2 bf16 [col][k]
#define OFF_PILBF    1103040      // 800*128*2 bf16
#define OFF_PILW4B   1307840      // 800*768*4 fp32
#define OFF_H3P      3765440      // 160000*128*2 bf16, SORTED rows (upper half hosts h2 temporarily)
#define WS_NEED      44725440

typedef __attribute__((ext_vector_type(8))) short bf16x8;
typedef __attribute__((ext_vector_type(4))) float f32x4;

typedef const __attribute__((address_space(1))) void gas_void;
typedef __attribute__((address_space(3))) void las_void;

__device__ __forceinline__ void gload_lds16(const void* g, void* l){
    __builtin_amdgcn_global_load_lds((gas_void*)g, (las_void*)l, 16, 0, 0);
}

__device__ __forceinline__ int binidx(float v){
    float t = v + 1.0f;
    t = fminf(fmaxf(t, 0.0f), 1.99f);
    return (int)(t / 0.2f);
}
__device__ __forceinline__ unsigned short f2bf(float f){
    unsigned u = __float_as_uint(f);
    u += 0x7fffu + ((u >> 16) & 1u);
    return (unsigned short)(u >> 16);
}
__device__ __forceinline__ unsigned u16max2(unsigned a, unsigned b){
    unsigned ah=a>>16, bh=b>>16, al=a&0xffffu, bl=b&0xffffu;
    return ((ah>bh?ah:bh)<<16) | (al>bl?al:bl);
}
__device__ __forceinline__ uint4 max16(uint4 a, uint4 b){
    uint4 r; r.x=u16max2(a.x,b.x); r.y=u16max2(a.y,b.y);
    r.z=u16max2(a.z,b.z); r.w=u16max2(a.w,b.w); return r;
}

// ---- kA: one batch per block (20000 = 32*625); 100-bin LDS histogram ----
__global__ __launch_bounds__(256) void kA(const float* __restrict__ x,
                                          int* __restrict__ segrank,
                                          int* __restrict__ counts,
                                          float* __restrict__ sums){
    __shared__ int   lc[NPIL];
    __shared__ float lsum[NPIL*3];
    __shared__ int   lbase[NPIL];
    int tid = threadIdx.x;
    if (tid < NPIL){
        lc[tid] = 0;
        lsum[3*tid] = 0.f; lsum[3*tid+1] = 0.f; lsum[3*tid+2] = 0.f;
    }
    __syncthreads();
    int i0  = blockIdx.x * 625;
    int bat = i0 / N_;                      // uniform within block
    int sv[3], lrv[3];
    #pragma unroll
    for (int t = 0; t < 3; t++){
        int ii = tid + t*256;
        int i  = i0 + ii;
        sv[t] = -1;
        if (ii < 625){
            float x0 = x[3*i], x1 = x[3*i+1], x2 = x[3*i+2];
            int s = binidx(x0)*G_ + binidx(x2);
            sv[t] = s;
            lrv[t] = atomicAdd(&lc[s], 1);
            atomicAdd(&lsum[s*3+0], x1);
            atomicAdd(&lsum[s*3+1], x0);
            atomicAdd(&lsum[s*3+2], x2);
        }
    }
    __syncthreads();
    if (tid < NPIL){
        int c = lc[tid];
        if (c > 0){
            int sb = bat*NPIL + tid;
            lbase[tid] = atomicAdd(&counts[sb], c);
            atomicAdd(&sums[3*sb+0], lsum[3*tid+0]);
            atomicAdd(&sums[3*sb+1], lsum[3*tid+1]);
            atomicAdd(&sums[3*sb+2], lsum[3*tid+2]);
        }
    }
    __syncthreads();
    #pragma unroll
    for (int t = 0; t < 3; t++){
        if (sv[t] >= 0){
            int i = i0 + tid + t*256;
            segrank[i] = (bat*NPIL + sv[t]) | ((lbase[sv[t]] + lrv[t]) << 10);
        }
    }
}

// ---- kScan: exclusive prefix sum over 800 counts (1 block) ----
__global__ __launch_bounds__(1024) void kScan(const int* __restrict__ counts,
                                              int* __restrict__ starts){
    __shared__ int s[1024];
    int t = threadIdx.x;
    int c = (t < NSB) ? counts[t] : 0;
    s[t] = c;
    __syncthreads();
    for (int off=1; off<1024; off<<=1){
        int v = (t >= off) ? s[t-off] : 0;
        __syncthreads();
        s[t] += v;
        __syncthreads();
    }
    if (t < NSB) starts[t] = s[t]-c;
    if (t == NSB) starts[NSB] = s[NSB-1];
}

// ---- kB: centroids + W3->bf16 [col][k] + W4T ----
__global__ __launch_bounds__(256) void kB(const int* __restrict__ counts,
                                          const float* __restrict__ sums,
                                          float* __restrict__ cent,
                                          const float* __restrict__ W3,
                                          unsigned short* __restrict__ W3bf,
                                          const float* __restrict__ W4,
                                          unsigned short* __restrict__ W4T){
    int idx = blockIdx.x*256 + threadIdx.x;
    if (idx < 2400){
        cent[idx] = sums[idx] / fmaxf((float)counts[idx/3], 1.0f);
    } else if (idx < 2400 + 8192){
        int t = idx - 2400;
        int col = t >> 6, k = t & 63;     // W3[k][col] -> W3bf[col][k]
        W3bf[t] = f2bf(W3[k*128 + col]);
    } else if (idx < 2400 + 8192 + 196608){
        int t = idx - 2400 - 8192;        // t = k*768 + j (coalesced read)
        int k = t / 768, j = t - k*768;
        W4T[j*256 + k] = f2bf(W4[t]);
    }
}

// ---- kC12: per-point layers 1+2 (fp32 VALU), h2 -> bf16 into UPPER half of h3p row ----
__global__ __launch_bounds__(256) void kC12(const float* __restrict__ x,
                                            const int* __restrict__ segrank,
                                            const int* __restrict__ starts,
                                            const float* __restrict__ cent,
                                            const float* __restrict__ W1,
                                            const float* __restrict__ W2,
                                            unsigned short* __restrict__ h3p){
    int i = blockIdx.x*256 + threadIdx.x;
    if (i >= NPTS) return;
    int pk = segrank[i];
    int sb = pk & 1023;
    int pos = starts[sb] + (pk >> 10);
    float p0 = x[3*i+1], p1 = x[3*i], p2 = x[3*i+2];
    float aug[6];
    aug[0]=p0; aug[1]=p1; aug[2]=p2;
    aug[3]=p0-cent[sb*3+0]; aug[4]=p1-cent[sb*3+1]; aug[5]=p2-cent[sb*3+2];

    float h1[32];
    #pragma unroll
    for (int j=0;j<32;j++){
        float a = 0.f;
        #pragma unroll
        for (int k=0;k<6;k++) a += aug[k]*W1[k*32+j];
        h1[j] = fmaxf(a, 0.f);
    }
    unsigned buf[32];
    #pragma unroll 8
    for (int jp=0;jp<32;jp++){
        float a0 = 0.f, a1 = 0.f;
        #pragma unroll
        for (int k=0;k<32;k++){
            a0 += h1[k]*W2[k*64 + jp*2];
            a1 += h1[k]*W2[k*64 + jp*2 + 1];
        }
        buf[jp] = (unsigned)f2bf(fmaxf(a0,0.f)) | ((unsigned)f2bf(fmaxf(a1,0.f)) << 16);
    }
    uint4* d4 = (uint4*)(h3p + (size_t)pos*128 + 64);
    #pragma unroll
    for (int q=0;q<8;q++) d4[q] = ((const uint4*)buf)[q];
}

// ---- kC3: MFMA GEMM h3[160000,128] = relu(h2[160000,64] @ W3), in place ----
__global__ __launch_bounds__(512) void kC3(const unsigned short* __restrict__ W3bf,
                                           unsigned short* __restrict__ h3p){
    __shared__ unsigned short Al[256*64];
    __shared__ unsigned short Bl[128*64];
    int tid = threadIdx.x;
    int m0  = blockIdx.x * 256;
    #pragma unroll
    for (int it=0; it<4; it++){
        int cc = tid + it*512;
        int row = cc >> 3, ch = cc & 7;
        int chs = ch ^ (row & 7);
        gload_lds16(h3p + (size_t)(m0+row)*128 + 64 + chs*8, (char*)Al + cc*16);
    }
    #pragma unroll
    for (int it=0; it<2; it++){
        int cc = tid + it*512;
        int row = cc >> 3, ch = cc & 7;
        int chs = ch ^ (row & 7);
        gload_lds16(W3bf + (size_t)row*64 + chs*8, (char*)Bl + cc*16);
    }
    __syncthreads();

    int lane = tid & 63, wid = tid >> 6;
    int wm = wid >> 1, wn = wid & 1;
    int l15 = lane & 15, lhi = lane >> 4;

    f32x4 acc[4][4];
    #pragma unroll
    for (int m=0;m<4;m++)
        #pragma unroll
        for (int n=0;n<4;n++) acc[m][n] = (f32x4){0.f,0.f,0.f,0.f};

    #pragma unroll
    for (int kk=0; kk<2; kk++){
        bf16x8 af[4], bfr[4];
        #pragma unroll
        for (int f=0; f<4; f++){
            int ra = wm*64 + f*16 + l15;
            af[f]  = *(const bf16x8*)((char*)Al + ra*128 + (((kk*4+lhi) ^ (ra&7))*16));
            int rb = wn*64 + f*16 + l15;
            bfr[f] = *(const bf16x8*)((char*)Bl + rb*128 + (((kk*4+lhi) ^ (rb&7))*16));
        }
        #pragma unroll
        for (int m=0;m<4;m++)
            #pragma unroll
            for (int n=0;n<4;n++)
                acc[m][n] = __builtin_amdgcn_mfma_f32_16x16x32_bf16(af[m], bfr[n], acc[m][n], 0,0,0);
    }

    #pragma unroll
    for (int m=0;m<4;m++)
        #pragma unroll
        for (int r=0;r<4;r++){
            int row = m0 + wm*64 + m*16 + lhi*4 + r;
            #pragma unroll
            for (int n=0;n<4;n++){
                int col = wn*64 + n*16 + l15;
                h3p[(size_t)row*128 + col] = f2bf(fmaxf(acc[m][n][r], 0.f));
            }
        }
}

// ---- kM: per-pillar segment-max of h3 (wide loads, LDS tree) ----
__global__ __launch_bounds__(256) void kM(const unsigned short* __restrict__ h3p,
                                          const int* __restrict__ starts,
                                          unsigned short* __restrict__ pilbf){
    __shared__ uint4 sd[16][16];
    int sb = blockIdx.x;
    int tx = threadIdx.x & 15, ty = threadIdx.x >> 4;
    int s = starts[sb], npts = starts[sb+1] - s;
    uint4 acc = {0u,0u,0u,0u};
    for (int p = ty; p < npts; p += 16){
        uint4 v = *(const uint4*)(h3p + (size_t)(s+p)*128 + tx*8);
        acc = max16(acc, v);
    }
    sd[ty][tx] = acc;
    __syncthreads();
    #pragma unroll
    for (int off=8; off; off>>=1){
        if (ty < off) sd[ty][tx] = max16(sd[ty][tx], sd[ty+off][tx]);
        __syncthreads();
    }
    if (ty == 0) *(uint4*)(pilbf + sb*128 + tx*8) = sd[0][tx];
}

// ---- kPB: MFMA GEMM pilW4b[800,768] = pilbf[800,128] @ W4[128:,:] ----
__global__ __launch_bounds__(256) void kPB(const unsigned short* __restrict__ pilbf,
                                           const unsigned short* __restrict__ W4T,
                                           float* __restrict__ pilW4b){
    __shared__ unsigned short Al[128*128];
    __shared__ unsigned short Bl[128*128];
    int m0 = blockIdx.x * 128;
    int n0 = blockIdx.y * 128;
    int tid = threadIdx.x;
    #pragma unroll
    for (int it=0; it<8; it++){
        int cc = tid + it*256;
        int row = cc >> 4, ch = cc & 15;
        int chs = ch ^ (row & 15);
        uint4 v = {0u,0u,0u,0u};
        if (m0 + row < NSB) v = *(const uint4*)(pilbf + (size_t)(m0+row)*128 + chs*8);
        *(uint4*)((char*)Al + cc*16) = v;
        uint4 vb = *(const uint4*)(W4T + (size_t)(n0+row)*256 + 128 + chs*8);
        *(uint4*)((char*)Bl + cc*16) = vb;
    }
    __syncthreads();
    int lane = tid & 63, wid = tid >> 6;
    int wm = wid >> 1, wn = wid & 1;
    int l15 = lane & 15, lhi = lane >> 4;
    f32x4 acc[4][4];
    #pragma unroll
    for (int m=0;m<4;m++)
        #pragma unroll
        for (int n=0;n<4;n++) acc[m][n] = (f32x4){0.f,0.f,0.f,0.f};
    #pragma unroll
    for (int kk=0; kk<4; kk++){
        bf16x8 af[4], bfr[4];
        #pragma unroll
        for (int f=0; f<4; f++){
            int ra = wm*64 + f*16 + l15;
            af[f]  = *(const bf16x8*)((char*)Al + ra*256 + (((kk*4+lhi) ^ (ra&15))*16));
            int rb = wn*64 + f*16 + l15;
            bfr[f] = *(const bf16x8*)((char*)Bl + rb*256 + (((kk*4+lhi) ^ (rb&15))*16));
        }
        #pragma unroll
        for (int m=0;m<4;m++)
            #pragma unroll
            for (int n=0;n<4;n++)
                acc[m][n] = __builtin_amdgcn_mfma_f32_16x16x32_bf16(af[m], bfr[n], acc[m][n], 0,0,0);
    }
    #pragma unroll
    for (int m=0;m<4;m++)
        #pragma unroll
        for (int r=0;r<4;r++){
            int p = wm*64 + m*16 + lhi*4 + r;
            int sbp = m0 + p;
            if (sbp < NSB){
                #pragma unroll
                for (int n=0;n<4;n++)
                    pilW4b[(size_t)sbp*768 + n0 + wn*64 + n*16 + l15] = acc[m][n][r];
            }
        }
}

// ---- kD: XCD-paired (sb,nt); DOUBLE-BUFFERED A with counted vmcnt (T3/T4);
//      64-row chunks via gload_lds; deferred bias+relu at final write ----
__global__ __launch_bounds__(256) void kD(const unsigned short* __restrict__ h3p,
                                          const int* __restrict__ starts,
                                          const float* __restrict__ pilW4b,
                                          const unsigned short* __restrict__ W4T,
                                          float* __restrict__ out){
    __shared__ unsigned short Al[2][64*128]; // 2 x 16KB
    __shared__ unsigned short Bl[128*128];   // 32KB
    __shared__ float red[2][2][64];
    int b  = blockIdx.x;
    int x_ = b & 7, t_ = b >> 3;
    int k_ = t_ / 6, nt = t_ - k_*6;
    int sb = x_ + 8*k_;
    int n0 = nt * 128;
    int tid = threadIdx.x;
    int start = starts[sb];
    int npts  = starts[sb+1] - start;
    if (npts == 0){
        if (tid < 128) out[(size_t)sb*768 + n0 + tid] = 0.f;
        return;
    }
    // stage B async (stays in flight until first counted wait)
    #pragma unroll
    for (int it=0; it<8; it++){
        int cc = tid + it*256;
        int row = cc >> 4, ch = cc & 15;
        int chs = ch ^ (row & 15);
        gload_lds16(W4T + (size_t)(n0+row)*256 + chs*8, (char*)Bl + cc*16);
    }
    int arow[4], achs[4];
    #pragma unroll
    for (int it=0; it<4; it++){
        int cc = tid + it*256;
        arow[it] = cc >> 4;
        achs[it] = (cc & 15) ^ (arow[it] & 15);
    }
    int lane = tid & 63, wid = tid >> 6;
    int wm = wid >> 1, wn = wid & 1;
    int l15 = lane & 15, lhi = lane >> 4;

    int nch = (npts + 63) >> 6;
    int tailr = npts & 63;

    // issue chunk 0 into Al[0] (clamped within pillar; extras masked at mx update)
    #pragma unroll
    for (int it=0; it<4; it++){
        int idx = arow[it] < npts ? arow[it] : npts-1;
        gload_lds16(h3p + (size_t)(start+idx)*128 + achs[it]*8,
                    (char*)Al[0] + (tid + it*256)*16);
    }

    float mx[2][4][4];
    #pragma unroll
    for (int m=0;m<2;m++)
        #pragma unroll
        for (int n=0;n<4;n++)
            #pragma unroll
            for (int r=0;r<4;r++) mx[m][n][r] = -3.0e38f;

    for (int c=0; c<nch; c++){
        if (c+1 < nch){
            int base = (c+1) << 6;
            #pragma unroll
            for (int it=0; it<4; it++){
                int idx = base + arow[it];
                idx = idx < npts ? idx : npts-1;
                gload_lds16(h3p + (size_t)(start+idx)*128 + achs[it]*8,
                            (char*)Al[(c+1)&1] + (tid + it*256)*16);
            }
            asm volatile("s_waitcnt vmcnt(4)" ::: "memory");   // chunk c (+B at c=0) landed; c+1 in flight
        } else {
            asm volatile("s_waitcnt vmcnt(0)" ::: "memory");   // last chunk: drain
        }
        __builtin_amdgcn_s_barrier();                          // all waves' chunk-c data visible

        const unsigned short* Ab = Al[c&1];
        f32x4 acc[2][4];
        #pragma unroll
        for (int m=0;m<2;m++)
            #pragma unroll
            for (int n=0;n<4;n++) acc[m][n] = (f32x4){0.f,0.f,0.f,0.f};
        #pragma unroll
        for (int kk=0; kk<4; kk++){
            bf16x8 af[2], bfr[4];
            #pragma unroll
            for (int f=0; f<2; f++){
                int ra = wm*32 + f*16 + l15;
                af[f] = *(const bf16x8*)((const char*)Ab + ra*256 + (((kk*4+lhi) ^ (ra&15))*16));
            }
            #pragma unroll
            for (int f=0; f<4; f++){
                int rb = wn*64 + f*16 + l15;
                bfr[f] = *(const bf16x8*)((const char*)Bl + rb*256 + (((kk*4+lhi) ^ (rb&15))*16));
            }
            #pragma unroll
            for (int m=0;m<2;m++)
                #pragma unroll
                for (int n=0;n<4;n++)
                    acc[m][n] = __builtin_amdgcn_mfma_f32_16x16x32_bf16(af[m], bfr[n], acc[m][n], 0,0,0);
        }
        if (c == nch-1 && tailr){
            #pragma unroll
            for (int m=0;m<2;m++)
                #pragma unroll
                for (int r=0;r<4;r++){
                    int p = wm*32 + m*16 + lhi*4 + r;
                    if (p < tailr){
                        #pragma unroll
                        for (int n=0;n<4;n++)
                            mx[m][n][r] = fmaxf(mx[m][n][r], acc[m][n][r]);
                    }
                }
        } else {
            #pragma unroll
            for (int m=0;m<2;m++)
                #pragma unroll
                for (int n=0;n<4;n++)
                    #pragma unroll
                    for (int r=0;r<4;r++)
                        mx[m][n][r] = fmaxf(mx[m][n][r], acc[m][n][r]);
        }
        __builtin_amdgcn_s_barrier();    // all waves done reading Al[c&1] before it is re-issued
    }

    float red4[4];
    #pragma unroll
    for (int n=0;n<4;n++){
        float v = -3.0e38f;
        #pragma unroll
        for (int m=0;m<2;m++)
            #pragma unroll
            for (int r=0;r<4;r++) v = fmaxf(v, mx[m][n][r]);
        v = fmaxf(v, __shfl_xor(v, 16));
        v = fmaxf(v, __shfl_xor(v, 32));
        red4[n] = v;
    }
    if (lhi == 0){
        #pragma unroll
        for (int n=0;n<4;n++) red[wm][wn][n*16 + l15] = red4[n];
    }
    __syncthreads();
    if (wm == 0){
        float v = fmaxf(red[0][wn][lane], red[1][wn][lane]);
        int col = n0 + wn*64 + lane;
        v = fmaxf(v + pilW4b[(size_t)sb*768 + col], 0.f);
        out[(size_t)sb*768 + col] = v;
    }
}

// ---- kE: per-pillar BatchNorm over (B, 768), in place ----
__global__ __launch_bounds__(256) void kE(float* __restrict__ out,
                                          const float* __restrict__ gamma,
                                          const float* __restrict__ beta){
    int p = blockIdx.x;
    int tid = threadIdx.x;
    float v[B_*3];
    float sum = 0.f, ssq = 0.f;
    #pragma unroll
    for (int b=0;b<B_;b++)
        #pragma unroll
        for (int r=0;r<3;r++){
            float t = out[(b*NPIL + p)*768 + tid + r*256];
            v[b*3+r] = t;
            sum += t; ssq += t*t;
        }
    #pragma unroll
    for (int off=32; off; off>>=1){
        sum += __shfl_xor(sum, off);
        ssq += __shfl_xor(ssq, off);
    }
    __shared__ float ls[8];
    __shared__ float sc[2];
    int lane = tid & 63, w = tid >> 6;
    if (lane == 0){ ls[w] = sum; ls[4+w] = ssq; }
    __syncthreads();
    if (tid == 0){
        float S = ls[0]+ls[1]+ls[2]+ls[3];
        float Q = ls[4]+ls[5]+ls[6]+ls[7];
        float mean = S * (1.0f/6144.0f);
        float var  = Q * (1.0f/6144.0f) - mean*mean;
        float scale = rsqrtf(var + BN_EPS) * gamma[p];
        sc[0] = scale;
        sc[1] = beta[p] - mean*scale;
    }
    __syncthreads();
    float scale = sc[0], shift = sc[1];
    #pragma unroll
    for (int b=0;b<B_;b++)
        #pragma unroll
        for (int r=0;r<3;r++)
            out[(b*NPIL + p)*768 + tid + r*256] = v[b*3+r]*scale + shift;
}

extern "C" void kernel_launch(void* const* d_in, const int* in_sizes, int n_in,
                              void* d_out, int out_size, void* d_ws, size_t ws_size,
                              hipStream_t stream){
    if (ws_size < (size_t)WS_NEED) return;
    const float* x     = (const float*)d_in[0];
    const float* W1    = (const float*)d_in[1];
    const float* W2    = (const float*)d_in[2];
    const float* W3    = (const float*)d_in[3];
    const float* W4    = (const float*)d_in[4];
    const float* gamma = (const float*)d_in[5];
    const float* beta  = (const float*)d_in[6];
    float* out = (float*)d_out;
    char*  ws  = (char*)d_ws;

    int*            counts = (int*)           (ws + OFF_COUNTS);
    float*          sums   = (float*)         (ws + OFF_SUMS);
    int*            starts = (int*)           (ws + OFF_STARTS);
    float*          cent   = (float*)         (ws + OFF_CENT);
    int*            segrank= (int*)           (ws + OFF_SEG);
    unsigned short* W3bf   = (unsigned short*)(ws + OFF_W3BF);
    unsigned short* W4T    = (unsigned short*)(ws + OFF_W4T);
    unsigned short* pilbf  = (unsigned short*)(ws + OFF_PILBF);
    float*          pilW4b = (float*)         (ws + OFF_PILW4B);
    unsigned short* h3p    = (unsigned short*)(ws + OFF_H3P);

    hipMemsetAsync(d_ws, 0, ZERO_BYTES, stream);

    kA<<<256, 256, 0, stream>>>(x, segrank, counts, sums);
    kScan<<<1, 1024, 0, stream>>>(counts, starts);
    kB<<<(2400+8192+196608+255)/256, 256, 0, stream>>>(counts, sums, cent, W3, W3bf, W4, W4T);
    kC12<<<(NPTS+255)/256, 256, 0, stream>>>(x, segrank, starts, cent, W1, W2, h3p);
    kC3<<<NPTS/256, 512, 0, stream>>>(W3bf, h3p);
    kM<<<NSB, 256, 0, stream>>>(h3p, starts, pilbf);
    dim3 gPB((NSB+127)/128, 6);
    kPB<<<gPB, 256, 0, stream>>>(pilbf, W4T, pilW4b);
    kD<<<4800, 256, 0, stream>>>(h3p, starts, pilW4b, W4T, out);
    kE<<<NPIL, 256, 0, stream>>>(out, gamma, beta);
}

// Round 18
// 173.083 us; speedup vs baseline: 1.1639x; 1.0165x over previous
//
#include <hip/hip_runtime.h>
#include <stdint.h>

#define B_    8
#define N_    20000
#define NPTS  (B_*N_)        // 160000
#define G_    10
#define NPIL  100
#define NSB   (B_*NPIL)      // 800 segments
#define BN_EPS 1e-5f

// ---- workspace layout (bytes) ----
#define OFF_COUNTS   0            // 800*4 = 3200
#define OFF_SUMS     3200         // 2400*4 = 9600
#define OFF_STARTS   12800        // 801*4
#define ZERO_BYTES   16320
#define OFF_CENT     19264        // 2400*4
#define OFF_SEG      28864        // 160000*4 (packed seg | rank<<10)
#define OFF_W3BF     668864       // 128*64*2 bf16 [col][k]
#define OFF_W4T      709824       // 768*256*2 bf16 [col][k]
#define OFF_PILBF    1103040      // 800*128*2 bf16
#define OFF_PILW4B   1307840      // 800*768*4 fp32
#define OFF_H3P      3765440      // 160000*128*2 bf16, SORTED rows (upper half hosts h2 temporarily)
#define WS_NEED      44725440

typedef __attribute__((ext_vector_type(8))) short bf16x8;
typedef __attribute__((ext_vector_type(4))) float f32x4;

typedef const __attribute__((address_space(1))) void gas_void;
typedef __attribute__((address_space(3))) void las_void;

__device__ __forceinline__ void gload_lds16(const void* g, void* l){
    __builtin_amdgcn_global_load_lds((gas_void*)g, (las_void*)l, 16, 0, 0);
}

__device__ __forceinline__ int binidx(float v){
    float t = v + 1.0f;
    t = fminf(fmaxf(t, 0.0f), 1.99f);
    return (int)(t / 0.2f);
}
__device__ __forceinline__ unsigned short f2bf(float f){
    unsigned u = __float_as_uint(f);
    u += 0x7fffu + ((u >> 16) & 1u);
    return (unsigned short)(u >> 16);
}
__device__ __forceinline__ unsigned u16max2(unsigned a, unsigned b){
    unsigned ah=a>>16, bh=b>>16, al=a&0xffffu, bl=b&0xffffu;
    return ((ah>bh?ah:bh)<<16) | (al>bl?al:bl);
}
__device__ __forceinline__ uint4 max16(uint4 a, uint4 b){
    uint4 r; r.x=u16max2(a.x,b.x); r.y=u16max2(a.y,b.y);
    r.z=u16max2(a.z,b.z); r.w=u16max2(a.w,b.w); return r;
}

// ---- kA: one batch per block (20000 = 32*625); 100-bin LDS histogram ----
__global__ __launch_bounds__(256) void kA(const float* __restrict__ x,
                                          int* __restrict__ segrank,
                                          int* __restrict__ counts,
                                          float* __restrict__ sums){
    __shared__ int   lc[NPIL];
    __shared__ float lsum[NPIL*3];
    __shared__ int   lbase[NPIL];
    int tid = threadIdx.x;
    if (tid < NPIL){
        lc[tid] = 0;
        lsum[3*tid] = 0.f; lsum[3*tid+1] = 0.f; lsum[3*tid+2] = 0.f;
    }
    __syncthreads();
    int i0  = blockIdx.x * 625;
    int bat = i0 / N_;                      // uniform within block
    int sv[3], lrv[3];
    #pragma unroll
    for (int t = 0; t < 3; t++){
        int ii = tid + t*256;
        int i  = i0 + ii;
        sv[t] = -1;
        if (ii < 625){
            float x0 = x[3*i], x1 = x[3*i+1], x2 = x[3*i+2];
            int s = binidx(x0)*G_ + binidx(x2);
            sv[t] = s;
            lrv[t] = atomicAdd(&lc[s], 1);
            atomicAdd(&lsum[s*3+0], x1);
            atomicAdd(&lsum[s*3+1], x0);
            atomicAdd(&lsum[s*3+2], x2);
        }
    }
    __syncthreads();
    if (tid < NPIL){
        int c = lc[tid];
        if (c > 0){
            int sb = bat*NPIL + tid;
            lbase[tid] = atomicAdd(&counts[sb], c);
            atomicAdd(&sums[3*sb+0], lsum[3*tid+0]);
            atomicAdd(&sums[3*sb+1], lsum[3*tid+1]);
            atomicAdd(&sums[3*sb+2], lsum[3*tid+2]);
        }
    }
    __syncthreads();
    #pragma unroll
    for (int t = 0; t < 3; t++){
        if (sv[t] >= 0){
            int i = i0 + tid + t*256;
            segrank[i] = (bat*NPIL + sv[t]) | ((lbase[sv[t]] + lrv[t]) << 10);
        }
    }
}

// ---- kScan: exclusive prefix sum over 800 counts (1 block) ----
__global__ __launch_bounds__(1024) void kScan(const int* __restrict__ counts,
                                              int* __restrict__ starts){
    __shared__ int s[1024];
    int t = threadIdx.x;
    int c = (t < NSB) ? counts[t] : 0;
    s[t] = c;
    __syncthreads();
    for (int off=1; off<1024; off<<=1){
        int v = (t >= off) ? s[t-off] : 0;
        __syncthreads();
        s[t] += v;
        __syncthreads();
    }
    if (t < NSB) starts[t] = s[t]-c;
    if (t == NSB) starts[NSB] = s[NSB-1];
}

// ---- kB: centroids + W3->bf16 [col][k] + W4T ----
__global__ __launch_bounds__(256) void kB(const int* __restrict__ counts,
                                          const float* __restrict__ sums,
                                          float* __restrict__ cent,
                                          const float* __restrict__ W3,
                                          unsigned short* __restrict__ W3bf,
                                          const float* __restrict__ W4,
                                          unsigned short* __restrict__ W4T){
    int idx = blockIdx.x*256 + threadIdx.x;
    if (idx < 2400){
        cent[idx] = sums[idx] / fmaxf((float)counts[idx/3], 1.0f);
    } else if (idx < 2400 + 8192){
        int t = idx - 2400;
        int col = t >> 6, k = t & 63;     // W3[k][col] -> W3bf[col][k]
        W3bf[t] = f2bf(W3[k*128 + col]);
    } else if (idx < 2400 + 8192 + 196608){
        int t = idx - 2400 - 8192;        // t = k*768 + j (coalesced read)
        int k = t / 768, j = t - k*768;
        W4T[j*256 + k] = f2bf(W4[t]);
    }
}

// ---- kC12: per-point layers 1+2 (fp32 VALU), h2 -> bf16 into UPPER half of h3p row ----
__global__ __launch_bounds__(256) void kC12(const float* __restrict__ x,
                                            const int* __restrict__ segrank,
                                            const int* __restrict__ starts,
                                            const float* __restrict__ cent,
                                            const float* __restrict__ W1,
                                            const float* __restrict__ W2,
                                            unsigned short* __restrict__ h3p){
    int i = blockIdx.x*256 + threadIdx.x;
    if (i >= NPTS) return;
    int pk = segrank[i];
    int sb = pk & 1023;
    int pos = starts[sb] + (pk >> 10);
    float p0 = x[3*i+1], p1 = x[3*i], p2 = x[3*i+2];
    float aug[6];
    aug[0]=p0; aug[1]=p1; aug[2]=p2;
    aug[3]=p0-cent[sb*3+0]; aug[4]=p1-cent[sb*3+1]; aug[5]=p2-cent[sb*3+2];

    float h1[32];
    #pragma unroll
    for (int j=0;j<32;j++){
        float a = 0.f;
        #pragma unroll
        for (int k=0;k<6;k++) a += aug[k]*W1[k*32+j];
        h1[j] = fmaxf(a, 0.f);
    }
    unsigned buf[32];
    #pragma unroll 8
    for (int jp=0;jp<32;jp++){
        float a0 = 0.f, a1 = 0.f;
        #pragma unroll
        for (int k=0;k<32;k++){
            a0 += h1[k]*W2[k*64 + jp*2];
            a1 += h1[k]*W2[k*64 + jp*2 + 1];
        }
        buf[jp] = (unsigned)f2bf(fmaxf(a0,0.f)) | ((unsigned)f2bf(fmaxf(a1,0.f)) << 16);
    }
    uint4* d4 = (uint4*)(h3p + (size_t)pos*128 + 64);
    #pragma unroll
    for (int q=0;q<8;q++) d4[q] = ((const uint4*)buf)[q];
}

// ---- kC3: MFMA GEMM h3[160000,128] = relu(h2[160000,64] @ W3), in place ----
__global__ __launch_bounds__(512) void kC3(const unsigned short* __restrict__ W3bf,
                                           unsigned short* __restrict__ h3p){
    __shared__ unsigned short Al[256*64];
    __shared__ unsigned short Bl[128*64];
    int tid = threadIdx.x;
    int m0  = blockIdx.x * 256;
    #pragma unroll
    for (int it=0; it<4; it++){
        int cc = tid + it*512;
        int row = cc >> 3, ch = cc & 7;
        int chs = ch ^ (row & 7);
        gload_lds16(h3p + (size_t)(m0+row)*128 + 64 + chs*8, (char*)Al + cc*16);
    }
    #pragma unroll
    for (int it=0; it<2; it++){
        int cc = tid + it*512;
        int row = cc >> 3, ch = cc & 7;
        int chs = ch ^ (row & 7);
        gload_lds16(W3bf + (size_t)row*64 + chs*8, (char*)Bl + cc*16);
    }
    __syncthreads();

    int lane = tid & 63, wid = tid >> 6;
    int wm = wid >> 1, wn = wid & 1;
    int l15 = lane & 15, lhi = lane >> 4;

    f32x4 acc[4][4];
    #pragma unroll
    for (int m=0;m<4;m++)
        #pragma unroll
        for (int n=0;n<4;n++) acc[m][n] = (f32x4){0.f,0.f,0.f,0.f};

    #pragma unroll
    for (int kk=0; kk<2; kk++){
        bf16x8 af[4], bfr[4];
        #pragma unroll
        for (int f=0; f<4; f++){
            int ra = wm*64 + f*16 + l15;
            af[f]  = *(const bf16x8*)((char*)Al + ra*128 + (((kk*4+lhi) ^ (ra&7))*16));
            int rb = wn*64 + f*16 + l15;
            bfr[f] = *(const bf16x8*)((char*)Bl + rb*128 + (((kk*4+lhi) ^ (rb&7))*16));
        }
        #pragma unroll
        for (int m=0;m<4;m++)
            #pragma unroll
            for (int n=0;n<4;n++)
                acc[m][n] = __builtin_amdgcn_mfma_f32_16x16x32_bf16(af[m], bfr[n], acc[m][n], 0,0,0);
    }

    #pragma unroll
    for (int m=0;m<4;m++)
        #pragma unroll
        for (int r=0;r<4;r++){
            int row = m0 + wm*64 + m*16 + lhi*4 + r;
            #pragma unroll
            for (int n=0;n<4;n++){
                int col = wn*64 + n*16 + l15;
                h3p[(size_t)row*128 + col] = f2bf(fmaxf(acc[m][n][r], 0.f));
            }
        }
}

// ---- kM: per-pillar segment-max of h3 (wide loads, LDS tree) ----
__global__ __launch_bounds__(256) void kM(const unsigned short* __restrict__ h3p,
                                          const int* __restrict__ starts,
                                          unsigned short* __restrict__ pilbf){
    __shared__ uint4 sd[16][16];
    int sb = blockIdx.x;
    int tx = threadIdx.x & 15, ty = threadIdx.x >> 4;
    int s = starts[sb], npts = starts[sb+1] - s;
    uint4 acc = {0u,0u,0u,0u};
    for (int p = ty; p < npts; p += 16){
        uint4 v = *(const uint4*)(h3p + (size_t)(s+p)*128 + tx*8);
        acc = max16(acc, v);
    }
    sd[ty][tx] = acc;
    __syncthreads();
    #pragma unroll
    for (int off=8; off; off>>=1){
        if (ty < off) sd[ty][tx] = max16(sd[ty][tx], sd[ty+off][tx]);
        __syncthreads();
    }
    if (ty == 0) *(uint4*)(pilbf + sb*128 + tx*8) = sd[0][tx];
}

// ---- kPB: MFMA GEMM pilW4b[800,768] = pilbf[800,128] @ W4[128:,:] ----
__global__ __launch_bounds__(256) void kPB(const unsigned short* __restrict__ pilbf,
                                           const unsigned short* __restrict__ W4T,
                                           float* __restrict__ pilW4b){
    __shared__ unsigned short Al[128*128];
    __shared__ unsigned short Bl[128*128];
    int m0 = blockIdx.x * 128;
    int n0 = blockIdx.y * 128;
    int tid = threadIdx.x;
    #pragma unroll
    for (int it=0; it<8; it++){
        int cc = tid + it*256;
        int row = cc >> 4, ch = cc & 15;
        int chs = ch ^ (row & 15);
        uint4 v = {0u,0u,0u,0u};
        if (m0 + row < NSB) v = *(const uint4*)(pilbf + (size_t)(m0+row)*128 + chs*8);
        *(uint4*)((char*)Al + cc*16) = v;
        uint4 vb = *(const uint4*)(W4T + (size_t)(n0+row)*256 + 128 + chs*8);
        *(uint4*)((char*)Bl + cc*16) = vb;
    }
    __syncthreads();
    int lane = tid & 63, wid = tid >> 6;
    int wm = wid >> 1, wn = wid & 1;
    int l15 = lane & 15, lhi = lane >> 4;
    f32x4 acc[4][4];
    #pragma unroll
    for (int m=0;m<4;m++)
        #pragma unroll
        for (int n=0;n<4;n++) acc[m][n] = (f32x4){0.f,0.f,0.f,0.f};
    #pragma unroll
    for (int kk=0; kk<4; kk++){
        bf16x8 af[4], bfr[4];
        #pragma unroll
        for (int f=0; f<4; f++){
            int ra = wm*64 + f*16 + l15;
            af[f]  = *(const bf16x8*)((char*)Al + ra*256 + (((kk*4+lhi) ^ (ra&15))*16));
            int rb = wn*64 + f*16 + l15;
            bfr[f] = *(const bf16x8*)((char*)Bl + rb*256 + (((kk*4+lhi) ^ (rb&15))*16));
        }
        #pragma unroll
        for (int m=0;m<4;m++)
            #pragma unroll
            for (int n=0;n<4;n++)
                acc[m][n] = __builtin_amdgcn_mfma_f32_16x16x32_bf16(af[m], bfr[n], acc[m][n], 0,0,0);
    }
    #pragma unroll
    for (int m=0;m<4;m++)
        #pragma unroll
        for (int r=0;r<4;r++){
            int p = wm*64 + m*16 + lhi*4 + r;
            int sbp = m0 + p;
            if (sbp < NSB){
                #pragma unroll
                for (int n=0;n<4;n++)
                    pilW4b[(size_t)sbp*768 + n0 + wn*64 + n*16 + l15] = acc[m][n][r];
            }
        }
}

// ---- kD: R13 inner structure; grid 2400, each block handles sb0 and sb0+400
//      (same XCD class, B staged once, per-block overheads amortized) ----
__global__ __launch_bounds__(256) void kD(const unsigned short* __restrict__ h3p,
                                          const int* __restrict__ starts,
                                          const float* __restrict__ pilW4b,
                                          const unsigned short* __restrict__ W4T,
                                          float* __restrict__ out){
    __shared__ unsigned short Al[64*128];    // 16KB
    __shared__ unsigned short Bl[128*128];   // 32KB
    __shared__ float red[2][2][64];
    int b  = blockIdx.x;
    int x_ = b & 7, t_ = b >> 3;
    int k_ = t_ / 6, nt = t_ - k_*6;         // k_ in 0..49
    int sb0 = x_ + 8*k_;                     // 0..399
    int n0 = nt * 128;
    int tid = threadIdx.x;
    // stage B async (drained by first chunk barrier)
    #pragma unroll
    for (int it=0; it<8; it++){
        int cc = tid + it*256;
        int row = cc >> 4, ch = cc & 15;
        int chs = ch ^ (row & 15);
        gload_lds16(W4T + (size_t)(n0+row)*256 + chs*8, (char*)Bl + cc*16);
    }
    int arow[4], achs[4];
    #pragma unroll
    for (int it=0; it<4; it++){
        int cc = tid + it*256;
        arow[it] = cc >> 4;
        achs[it] = (cc & 15) ^ (arow[it] & 15);
    }
    int lane = tid & 63, wid = tid >> 6;
    int wm = wid >> 1, wn = wid & 1;
    int l15 = lane & 15, lhi = lane >> 4;

    #pragma unroll
    for (int pp=0; pp<2; pp++){
        int sb = sb0 + pp*400;
        int start = starts[sb];
        int npts  = starts[sb+1] - start;
        if (npts == 0){
            __syncthreads();                 // keep barrier pattern uniform
            if (tid < 128) out[(size_t)sb*768 + n0 + tid] = 0.f;
            continue;
        }
        const unsigned short* asrc[4];
        #pragma unroll
        for (int it=0; it<4; it++)
            asrc[it] = h3p + (size_t)(start+arow[it])*128 + achs[it]*8;

        float mx[2][4][4];
        #pragma unroll
        for (int m=0;m<2;m++)
            #pragma unroll
            for (int n=0;n<4;n++)
                #pragma unroll
                for (int r=0;r<4;r++) mx[m][n][r] = -3.0e38f;

        int nfull = npts >> 6;
        int tailr = npts & 63;

        for (int c=0; c<nfull; c++){
            __syncthreads();
            #pragma unroll
            for (int it=0; it<4; it++){
                gload_lds16(asrc[it], (char*)Al + (tid + it*256)*16);
                asrc[it] += 64*128;
            }
            __syncthreads();
            f32x4 acc[2][4];
            #pragma unroll
            for (int m=0;m<2;m++)
                #pragma unroll
                for (int n=0;n<4;n++) acc[m][n] = (f32x4){0.f,0.f,0.f,0.f};
            #pragma unroll
            for (int kk=0; kk<4; kk++){
                bf16x8 af[2], bfr[4];
                #pragma unroll
                for (int f=0; f<2; f++){
                    int ra = wm*32 + f*16 + l15;
                    af[f] = *(const bf16x8*)((const char*)Al + ra*256 + (((kk*4+lhi) ^ (ra&15))*16));
                }
                #pragma unroll
                for (int f=0; f<4; f++){
                    int rb = wn*64 + f*16 + l15;
                    bfr[f] = *(const bf16x8*)((const char*)Bl + rb*256 + (((kk*4+lhi) ^ (rb&15))*16));
                }
                #pragma unroll
                for (int m=0;m<2;m++)
                    #pragma unroll
                    for (int n=0;n<4;n++)
                        acc[m][n] = __builtin_amdgcn_mfma_f32_16x16x32_bf16(af[m], bfr[n], acc[m][n], 0,0,0);
            }
            #pragma unroll
            for (int m=0;m<2;m++)
                #pragma unroll
                for (int n=0;n<4;n++)
                    #pragma unroll
                    for (int r=0;r<4;r++)
                        mx[m][n][r] = fmaxf(mx[m][n][r], acc[m][n][r]);
        }
        if (tailr > 0){
            int base = nfull << 6;
            __syncthreads();
            #pragma unroll
            for (int it=0; it<4; it++){
                int idx = start + base + arow[it];
                idx = idx < NPTS ? idx : NPTS-1;   // clamp; excluded by predicate below
                gload_lds16(h3p + (size_t)idx*128 + achs[it]*8, (char*)Al + (tid + it*256)*16);
            }
            __syncthreads();
            f32x4 acc[2][4];
            #pragma unroll
            for (int m=0;m<2;m++)
                #pragma unroll
                for (int n=0;n<4;n++) acc[m][n] = (f32x4){0.f,0.f,0.f,0.f};
            #pragma unroll
            for (int kk=0; kk<4; kk++){
                bf16x8 af[2], bfr[4];
                #pragma unroll
                for (int f=0; f<2; f++){
                    int ra = wm*32 + f*16 + l15;
                    af[f] = *(const bf16x8*)((const char*)Al + ra*256 + (((kk*4+lhi) ^ (ra&15))*16));
                }
                #pragma unroll
                for (int f=0; f<4; f++){
                    int rb = wn*64 + f*16 + l15;
                    bfr[f] = *(const bf16x8*)((const char*)Bl + rb*256 + (((kk*4+lhi) ^ (rb&15))*16));
                }
                #pragma unroll
                for (int m=0;m<2;m++)
                    #pragma unroll
                    for (int n=0;n<4;n++)
                        acc[m][n] = __builtin_amdgcn_mfma_f32_16x16x32_bf16(af[m], bfr[n], acc[m][n], 0,0,0);
            }
            #pragma unroll
            for (int m=0;m<2;m++)
                #pragma unroll
                for (int r=0;r<4;r++){
                    int p = wm*32 + m*16 + lhi*4 + r;
                    if (p < tailr){
                        #pragma unroll
                        for (int n=0;n<4;n++)
                            mx[m][n][r] = fmaxf(mx[m][n][r], acc[m][n][r]);
                    }
                }
        }

        float red4[4];
        #pragma unroll
        for (int n=0;n<4;n++){
            float v = -3.0e38f;
            #pragma unroll
            for (int m=0;m<2;m++)
                #pragma unroll
                for (int r=0;r<4;r++) v = fmaxf(v, mx[m][n][r]);
            v = fmaxf(v, __shfl_xor(v, 16));
            v = fmaxf(v, __shfl_xor(v, 32));
            red4[n] = v;
        }
        __syncthreads();                     // mx/red region reuse safe across pillars
        if (lhi == 0){
            #pragma unroll
            for (int n=0;n<4;n++) red[wm][wn][n*16 + l15] = red4[n];
        }
        __syncthreads();
        if (wm == 0){
            float v = fmaxf(red[0][wn][lane], red[1][wn][lane]);
            int col = n0 + wn*64 + lane;
            v = fmaxf(v + pilW4b[(size_t)sb*768 + col], 0.f);
            out[(size_t)sb*768 + col] = v;
        }
    }
}

// ---- kE: per-pillar BatchNorm over (B, 768), in place ----
__global__ __launch_bounds__(256) void kE(float* __restrict__ out,
                                          const float* __restrict__ gamma,
                                          const float* __restrict__ beta){
    int p = blockIdx.x;
    int tid = threadIdx.x;
    float v[B_*3];
    float sum = 0.f, ssq = 0.f;
    #pragma unroll
    for (int b=0;b<B_;b++)
        #pragma unroll
        for (int r=0;r<3;r++){
            float t = out[(b*NPIL + p)*768 + tid + r*256];
            v[b*3+r] = t;
            sum += t; ssq += t*t;
        }
    #pragma unroll
    for (int off=32; off; off>>=1){
        sum += __shfl_xor(sum, off);
        ssq += __shfl_xor(ssq, off);
    }
    __shared__ float ls[8];
    __shared__ float sc[2];
    int lane = tid & 63, w = tid >> 6;
    if (lane == 0){ ls[w] = sum; ls[4+w] = ssq; }
    __syncthreads();
    if (tid == 0){
        float S = ls[0]+ls[1]+ls[2]+ls[3];
        float Q = ls[4]+ls[5]+ls[6]+ls[7];
        float mean = S * (1.0f/6144.0f);
        float var  = Q * (1.0f/6144.0f) - mean*mean;
        float scale = rsqrtf(var + BN_EPS) * gamma[p];
        sc[0] = scale;
        sc[1] = beta[p] - mean*scale;
    }
    __syncthreads();
    float scale = sc[0], shift = sc[1];
    #pragma unroll
    for (int b=0;b<B_;b++)
        #pragma unroll
        for (int r=0;r<3;r++)
            out[(b*NPIL + p)*768 + tid + r*256] = v[b*3+r]*scale + shift;
}

extern "C" void kernel_launch(void* const* d_in, const int* in_sizes, int n_in,
                              void* d_out, int out_size, void* d_ws, size_t ws_size,
                              hipStream_t stream){
    if (ws_size < (size_t)WS_NEED) return;
    const float* x     = (const float*)d_in[0];
    const float* W1    = (const float*)d_in[1];
    const float* W2    = (const float*)d_in[2];
    const float* W3    = (const float*)d_in[3];
    const float* W4    = (const float*)d_in[4];
    const float* gamma = (const float*)d_in[5];
    const float* beta  = (const float*)d_in[6];
    float* out = (float*)d_out;
    char*  ws  = (char*)d_ws;

    int*            counts = (int*)           (ws + OFF_COUNTS);
    float*          sums   = (float*)         (ws + OFF_SUMS);
    int*            starts = (int*)           (ws + OFF_STARTS);
    float*          cent   = (float*)         (ws + OFF_CENT);
    int*            segrank= (int*)           (ws + OFF_SEG);
    unsigned short* W3bf   = (unsigned short*)(ws + OFF_W3BF);
    unsigned short* W4T    = (unsigned short*)(ws + OFF_W4T);
    unsigned short* pilbf  = (unsigned short*)(ws + OFF_PILBF);
    float*          pilW4b = (float*)         (ws + OFF_PILW4B);
    unsigned short* h3p    = (unsigned short*)(ws + OFF_H3P);

    hipMemsetAsync(d_ws, 0, ZERO_BYTES, stream);

    kA<<<256, 256, 0, stream>>>(x, segrank, counts, sums);
    kScan<<<1, 1024, 0, stream>>>(counts, starts);
    kB<<<(2400+8192+196608+255)/256, 256, 0, stream>>>(counts, sums, cent, W3, W3bf, W4, W4T);
    kC12<<<(NPTS+255)/256, 256, 0, stream>>>(x, segrank, starts, cent, W1, W2, h3p);
    kC3<<<NPTS/256, 512, 0, stream>>>(W3bf, h3p);
    kM<<<NSB, 256, 0, stream>>>(h3p, starts, pilbf);
    dim3 gPB((NSB+127)/128, 6);
    kPB<<<gPB, 256, 0, stream>>>(pilbf, W4T, pilW4b);
    kD<<<2400, 256, 0, stream>>>(h3p, starts, pilW4b, W4T, out);
    kE<<<NPIL, 256, 0, stream>>>(out, gamma, beta);
}

// Round 19
// 164.298 us; speedup vs baseline: 1.2261x; 1.0535x over previous
//
#include <hip/hip_runtime.h>
#include <stdint.h>

#define B_    8
#define N_    20000
#define NPTS  (B_*N_)        // 160000
#define G_    10
#define NPIL  100
#define NSB   (B_*NPIL)      // 800 segments
#define BN_EPS 1e-5f

// ---- workspace layout (bytes) ----
#define OFF_COUNTS   0            // 800*4 = 3200
#define OFF_SUMS     3200         // 2400*4 = 9600
#define OFF_STARTS   12800        // 801*4
#define ZERO_BYTES   16320
#define OFF_CENT     19264        // 2400*4
#define OFF_SEG      28864        // 160000*4 (packed seg | rank<<10)
#define OFF_W3BF     668864       // 128*64*2 bf16 [col][k]
#define OFF_W4T      709824       // 768*256*2 bf16 [col][k]
#define OFF_PILBF    1103040      // 800*128*2 bf16
#define OFF_PILW4B   1307840      // 800*768*4 fp32
#define OFF_H3P      3765440      // 160000*128*2 bf16, SORTED rows (upper half hosts h2 temporarily)
#define WS_NEED      44725440

typedef __attribute__((ext_vector_type(8))) short bf16x8;
typedef __attribute__((ext_vector_type(4))) float f32x4;

typedef const __attribute__((address_space(1))) void gas_void;
typedef __attribute__((address_space(3))) void las_void;

__device__ __forceinline__ void gload_lds16(const void* g, void* l){
    __builtin_amdgcn_global_load_lds((gas_void*)g, (las_void*)l, 16, 0, 0);
}

__device__ __forceinline__ int binidx(float v){
    float t = v + 1.0f;
    t = fminf(fmaxf(t, 0.0f), 1.99f);
    return (int)(t / 0.2f);
}
__device__ __forceinline__ unsigned short f2bf(float f){
    unsigned u = __float_as_uint(f);
    u += 0x7fffu + ((u >> 16) & 1u);
    return (unsigned short)(u >> 16);
}
__device__ __forceinline__ unsigned u16max2(unsigned a, unsigned b){
    unsigned ah=a>>16, bh=b>>16, al=a&0xffffu, bl=b&0xffffu;
    return ((ah>bh?ah:bh)<<16) | (al>bl?al:bl);
}
__device__ __forceinline__ uint4 max16(uint4 a, uint4 b){
    uint4 r; r.x=u16max2(a.x,b.x); r.y=u16max2(a.y,b.y);
    r.z=u16max2(a.z,b.z); r.w=u16max2(a.w,b.w); return r;
}

// shared MFMA chunk body for kD (64 rows x 128 cols, K=128, &15 swizzle)
__device__ __forceinline__ void kd_mfma(const unsigned short* Al, const unsigned short* Bl,
                                        int wm, int wn, int l15, int lhi, f32x4 acc[2][4]){
    #pragma unroll
    for (int kk=0; kk<4; kk++){
        bf16x8 af[2], bfr[4];
        #pragma unroll
        for (int f=0; f<2; f++){
            int ra = wm*32 + f*16 + l15;
            af[f]  = *(const bf16x8*)((const char*)Al + ra*256 + (((kk*4+lhi) ^ (ra&15))*16));
        }
        #pragma unroll
        for (int f=0; f<4; f++){
            int rb = wn*64 + f*16 + l15;
            bfr[f] = *(const bf16x8*)((const char*)Bl + rb*256 + (((kk*4+lhi) ^ (rb&15))*16));
        }
        #pragma unroll
        for (int m=0;m<2;m++)
            #pragma unroll
            for (int n=0;n<4;n++)
                acc[m][n] = __builtin_amdgcn_mfma_f32_16x16x32_bf16(af[m], bfr[n], acc[m][n], 0,0,0);
    }
}

// ---- kA: one batch per block (20000 = 32*625); 100-bin LDS histogram ----
__global__ __launch_bounds__(256) void kA(const float* __restrict__ x,
                                          int* __restrict__ segrank,
                                          int* __restrict__ counts,
                                          float* __restrict__ sums){
    __shared__ int   lc[NPIL];
    __shared__ float lsum[NPIL*3];
    __shared__ int   lbase[NPIL];
    int tid = threadIdx.x;
    if (tid < NPIL){
        lc[tid] = 0;
        lsum[3*tid] = 0.f; lsum[3*tid+1] = 0.f; lsum[3*tid+2] = 0.f;
    }
    __syncthreads();
    int i0  = blockIdx.x * 625;
    int bat = i0 / N_;                      // uniform within block
    int sv[3], lrv[3];
    #pragma unroll
    for (int t = 0; t < 3; t++){
        int ii = tid + t*256;
        int i  = i0 + ii;
        sv[t] = -1;
        if (ii < 625){
            float x0 = x[3*i], x1 = x[3*i+1], x2 = x[3*i+2];
            int s = binidx(x0)*G_ + binidx(x2);
            sv[t] = s;
            lrv[t] = atomicAdd(&lc[s], 1);
            atomicAdd(&lsum[s*3+0], x1);
            atomicAdd(&lsum[s*3+1], x0);
            atomicAdd(&lsum[s*3+2], x2);
        }
    }
    __syncthreads();
    if (tid < NPIL){
        int c = lc[tid];
        if (c > 0){
            int sb = bat*NPIL + tid;
            lbase[tid] = atomicAdd(&counts[sb], c);
            atomicAdd(&sums[3*sb+0], lsum[3*tid+0]);
            atomicAdd(&sums[3*sb+1], lsum[3*tid+1]);
            atomicAdd(&sums[3*sb+2], lsum[3*tid+2]);
        }
    }
    __syncthreads();
    #pragma unroll
    for (int t = 0; t < 3; t++){
        if (sv[t] >= 0){
            int i = i0 + tid + t*256;
            segrank[i] = (bat*NPIL + sv[t]) | ((lbase[sv[t]] + lrv[t]) << 10);
        }
    }
}

// ---- kScan: exclusive prefix sum over 800 counts (1 block) ----
__global__ __launch_bounds__(1024) void kScan(const int* __restrict__ counts,
                                              int* __restrict__ starts){
    __shared__ int s[1024];
    int t = threadIdx.x;
    int c = (t < NSB) ? counts[t] : 0;
    s[t] = c;
    __syncthreads();
    for (int off=1; off<1024; off<<=1){
        int v = (t >= off) ? s[t-off] : 0;
        __syncthreads();
        s[t] += v;
        __syncthreads();
    }
    if (t < NSB) starts[t] = s[t]-c;
    if (t == NSB) starts[NSB] = s[NSB-1];
}

// ---- kB: centroids + W3->bf16 [col][k] + W4T ----
__global__ __launch_bounds__(256) void kB(const int* __restrict__ counts,
                                          const float* __restrict__ sums,
                                          float* __restrict__ cent,
                                          const float* __restrict__ W3,
                                          unsigned short* __restrict__ W3bf,
                                          const float* __restrict__ W4,
                                          unsigned short* __restrict__ W4T){
    int idx = blockIdx.x*256 + threadIdx.x;
    if (idx < 2400){
        cent[idx] = sums[idx] / fmaxf((float)counts[idx/3], 1.0f);
    } else if (idx < 2400 + 8192){
        int t = idx - 2400;
        int col = t >> 6, k = t & 63;     // W3[k][col] -> W3bf[col][k]
        W3bf[t] = f2bf(W3[k*128 + col]);
    } else if (idx < 2400 + 8192 + 196608){
        int t = idx - 2400 - 8192;        // t = k*768 + j (coalesced read)
        int k = t / 768, j = t - k*768;
        W4T[j*256 + k] = f2bf(W4[t]);
    }
}

// ---- kC12: per-point layers 1+2 (fp32 VALU), h2 -> bf16 into UPPER half of h3p row ----
__global__ __launch_bounds__(256) void kC12(const float* __restrict__ x,
                                            const int* __restrict__ segrank,
                                            const int* __restrict__ starts,
                                            const float* __restrict__ cent,
                                            const float* __restrict__ W1,
                                            const float* __restrict__ W2,
                                            unsigned short* __restrict__ h3p){
    int i = blockIdx.x*256 + threadIdx.x;
    if (i >= NPTS) return;
    int pk = segrank[i];
    int sb = pk & 1023;
    int pos = starts[sb] + (pk >> 10);
    float p0 = x[3*i+1], p1 = x[3*i], p2 = x[3*i+2];
    float aug[6];
    aug[0]=p0; aug[1]=p1; aug[2]=p2;
    aug[3]=p0-cent[sb*3+0]; aug[4]=p1-cent[sb*3+1]; aug[5]=p2-cent[sb*3+2];

    float h1[32];
    #pragma unroll
    for (int j=0;j<32;j++){
        float a = 0.f;
        #pragma unroll
        for (int k=0;k<6;k++) a += aug[k]*W1[k*32+j];
        h1[j] = fmaxf(a, 0.f);
    }
    unsigned buf[32];
    #pragma unroll 8
    for (int jp=0;jp<32;jp++){
        float a0 = 0.f, a1 = 0.f;
        #pragma unroll
        for (int k=0;k<32;k++){
            a0 += h1[k]*W2[k*64 + jp*2];
            a1 += h1[k]*W2[k*64 + jp*2 + 1];
        }
        buf[jp] = (unsigned)f2bf(fmaxf(a0,0.f)) | ((unsigned)f2bf(fmaxf(a1,0.f)) << 16);
    }
    uint4* d4 = (uint4*)(h3p + (size_t)pos*128 + 64);
    #pragma unroll
    for (int q=0;q<8;q++) d4[q] = ((const uint4*)buf)[q];
}

// ---- kC3: MFMA GEMM h3[160000,128] = relu(h2[160000,64] @ W3), in place ----
__global__ __launch_bounds__(512) void kC3(const unsigned short* __restrict__ W3bf,
                                           unsigned short* __restrict__ h3p){
    __shared__ unsigned short Al[256*64];
    __shared__ unsigned short Bl[128*64];
    int tid = threadIdx.x;
    int m0  = blockIdx.x * 256;
    #pragma unroll
    for (int it=0; it<4; it++){
        int cc = tid + it*512;
        int row = cc >> 3, ch = cc & 7;
        int chs = ch ^ (row & 7);
        gload_lds16(h3p + (size_t)(m0+row)*128 + 64 + chs*8, (char*)Al + cc*16);
    }
    #pragma unroll
    for (int it=0; it<2; it++){
        int cc = tid + it*512;
        int row = cc >> 3, ch = cc & 7;
        int chs = ch ^ (row & 7);
        gload_lds16(W3bf + (size_t)row*64 + chs*8, (char*)Bl + cc*16);
    }
    __syncthreads();

    int lane = tid & 63, wid = tid >> 6;
    int wm = wid >> 1, wn = wid & 1;
    int l15 = lane & 15, lhi = lane >> 4;

    f32x4 acc[4][4];
    #pragma unroll
    for (int m=0;m<4;m++)
        #pragma unroll
        for (int n=0;n<4;n++) acc[m][n] = (f32x4){0.f,0.f,0.f,0.f};

    #pragma unroll
    for (int kk=0; kk<2; kk++){
        bf16x8 af[4], bfr[4];
        #pragma unroll
        for (int f=0; f<4; f++){
            int ra = wm*64 + f*16 + l15;
            af[f]  = *(const bf16x8*)((char*)Al + ra*128 + (((kk*4+lhi) ^ (ra&7))*16));
            int rb = wn*64 + f*16 + l15;
            bfr[f] = *(const bf16x8*)((char*)Bl + rb*128 + (((kk*4+lhi) ^ (rb&7))*16));
        }
        #pragma unroll
        for (int m=0;m<4;m++)
            #pragma unroll
            for (int n=0;n<4;n++)
                acc[m][n] = __builtin_amdgcn_mfma_f32_16x16x32_bf16(af[m], bfr[n], acc[m][n], 0,0,0);
    }

    #pragma unroll
    for (int m=0;m<4;m++)
        #pragma unroll
        for (int r=0;r<4;r++){
            int row = m0 + wm*64 + m*16 + lhi*4 + r;
            #pragma unroll
            for (int n=0;n<4;n++){
                int col = wn*64 + n*16 + l15;
                h3p[(size_t)row*128 + col] = f2bf(fmaxf(acc[m][n][r], 0.f));
            }
        }
}

// ---- kM: per-pillar segment-max of h3 (wide loads, LDS tree) ----
__global__ __launch_bounds__(256) void kM(const unsigned short* __restrict__ h3p,
                                          const int* __restrict__ starts,
                                          unsigned short* __restrict__ pilbf){
    __shared__ uint4 sd[16][16];
    int sb = blockIdx.x;
    int tx = threadIdx.x & 15, ty = threadIdx.x >> 4;
    int s = starts[sb], npts = starts[sb+1] - s;
    uint4 acc = {0u,0u,0u,0u};
    for (int p = ty; p < npts; p += 16){
        uint4 v = *(const uint4*)(h3p + (size_t)(s+p)*128 + tx*8);
        acc = max16(acc, v);
    }
    sd[ty][tx] = acc;
    __syncthreads();
    #pragma unroll
    for (int off=8; off; off>>=1){
        if (ty < off) sd[ty][tx] = max16(sd[ty][tx], sd[ty+off][tx]);
        __syncthreads();
    }
    if (ty == 0) *(uint4*)(pilbf + sb*128 + tx*8) = sd[0][tx];
}

// ---- kPB: MFMA GEMM pilW4b[800,768] = pilbf[800,128] @ W4[128:,:] ----
__global__ __launch_bounds__(256) void kPB(const unsigned short* __restrict__ pilbf,
                                           const unsigned short* __restrict__ W4T,
                                           float* __restrict__ pilW4b){
    __shared__ unsigned short Al[128*128];
    __shared__ unsigned short Bl[128*128];
    int m0 = blockIdx.x * 128;
    int n0 = blockIdx.y * 128;
    int tid = threadIdx.x;
    #pragma unroll
    for (int it=0; it<8; it++){
        int cc = tid + it*256;
        int row = cc >> 4, ch = cc & 15;
        int chs = ch ^ (row & 15);
        uint4 v = {0u,0u,0u,0u};
        if (m0 + row < NSB) v = *(const uint4*)(pilbf + (size_t)(m0+row)*128 + chs*8);
        *(uint4*)((char*)Al + cc*16) = v;
        uint4 vb = *(const uint4*)(W4T + (size_t)(n0+row)*256 + 128 + chs*8);
        *(uint4*)((char*)Bl + cc*16) = vb;
    }
    __syncthreads();
    int lane = tid & 63, wid = tid >> 6;
    int wm = wid >> 1, wn = wid & 1;
    int l15 = lane & 15, lhi = lane >> 4;
    f32x4 acc[4][4];
    #pragma unroll
    for (int m=0;m<4;m++)
        #pragma unroll
        for (int n=0;n<4;n++) acc[m][n] = (f32x4){0.f,0.f,0.f,0.f};
    #pragma unroll
    for (int kk=0; kk<4; kk++){
        bf16x8 af[4], bfr[4];
        #pragma unroll
        for (int f=0; f<4; f++){
            int ra = wm*64 + f*16 + l15;
            af[f]  = *(const bf16x8*)((char*)Al + ra*256 + (((kk*4+lhi) ^ (ra&15))*16));
            int rb = wn*64 + f*16 + l15;
            bfr[f] = *(const bf16x8*)((char*)Bl + rb*256 + (((kk*4+lhi) ^ (rb&15))*16));
        }
        #pragma unroll
        for (int m=0;m<4;m++)
            #pragma unroll
            for (int n=0;n<4;n++)
                acc[m][n] = __builtin_amdgcn_mfma_f32_16x16x32_bf16(af[m], bfr[n], acc[m][n], 0,0,0);
    }
    #pragma unroll
    for (int m=0;m<4;m++)
        #pragma unroll
        for (int r=0;r<4;r++){
            int p = wm*64 + m*16 + lhi*4 + r;
            int sbp = m0 + p;
            if (sbp < NSB){
                #pragma unroll
                for (int n=0;n<4;n++)
                    pilW4b[(size_t)sbp*768 + n0 + wn*64 + n*16 + l15] = acc[m][n][r];
            }
        }
}

// ---- kD: XCD-paired (sb,nt); async gload_lds; 64-row chunks; peeled full/tail:
//      full chunks predicate-free with hoisted src pointers; tail clamped+predicated ----
__global__ __launch_bounds__(256) void kD(const unsigned short* __restrict__ h3p,
                                          const int* __restrict__ starts,
                                          const float* __restrict__ pilW4b,
                                          const unsigned short* __restrict__ W4T,
                                          float* __restrict__ out){
    __shared__ unsigned short Al[64*128];    // 16KB
    __shared__ unsigned short Bl[128*128];   // 32KB
    __shared__ float red[2][2][64];
    int b  = blockIdx.x;
    int x_ = b & 7, t_ = b >> 3;
    int k_ = t_ / 6, nt = t_ - k_*6;
    int sb = x_ + 8*k_;
    int n0 = nt * 128;
    int tid = threadIdx.x;
    int start = starts[sb];
    int npts  = starts[sb+1] - start;
    if (npts == 0){
        if (tid < 128) out[(size_t)sb*768 + n0 + tid] = 0.f;
        return;
    }
    // stage B async (in flight until first barrier)
    #pragma unroll
    for (int it=0; it<8; it++){
        int cc = tid + it*256;
        int row = cc >> 4, ch = cc & 15;
        int chs = ch ^ (row & 15);
        gload_lds16(W4T + (size_t)(n0+row)*256 + chs*8, (char*)Bl + cc*16);
    }
    // hoisted per-thread A-stage source pointers (advance 64 rows = 16KB per chunk)
    const unsigned short* asrc[4];
    int arow[4];
    #pragma unroll
    for (int it=0; it<4; it++){
        int cc = tid + it*256;
        int row = cc >> 4, ch = cc & 15;
        int chs = ch ^ (row & 15);
        arow[it] = row;
        asrc[it] = h3p + (size_t)(start+row)*128 + chs*8;
    }
    int lane = tid & 63, wid = tid >> 6;
    int wm = wid >> 1, wn = wid & 1;
    int l15 = lane & 15, lhi = lane >> 4;

    float mx[2][4][4];
    #pragma unroll
    for (int m=0;m<2;m++)
        #pragma unroll
        for (int n=0;n<4;n++)
            #pragma unroll
            for (int r=0;r<4;r++) mx[m][n][r] = -3.0e38f;

    int nfull = npts >> 6;
    int tailr = npts - (nfull << 6);

    for (int c=0; c<nfull; c++){
        __syncthreads();
        #pragma unroll
        for (int it=0; it<4; it++){
            gload_lds16(asrc[it], (char*)Al + (tid + it*256)*16);
            asrc[it] += 64*128;
        }
        __syncthreads();
        f32x4 acc[2][4];
        #pragma unroll
        for (int m=0;m<2;m++)
            #pragma unroll
            for (int n=0;n<4;n++) acc[m][n] = (f32x4){0.f,0.f,0.f,0.f};
        kd_mfma(Al, Bl, wm, wn, l15, lhi, acc);
        #pragma unroll
        for (int m=0;m<2;m++)
            #pragma unroll
            for (int n=0;n<4;n++)
                #pragma unroll
                for (int r=0;r<4;r++)
                    mx[m][n][r] = fmaxf(mx[m][n][r], acc[m][n][r]);
    }
    if (tailr > 0){
        int base = nfull << 6;
        __syncthreads();
        #pragma unroll
        for (int it=0; it<4; it++){
            // rows >= npts read neighbor data (in-bounds via clamp); excluded by predicate
            int idx = start + base + arow[it];
            idx = idx < NPTS ? idx : NPTS-1;
            int cc = tid + it*256;
            int chs = (cc & 15) ^ (arow[it] & 15);
            gload_lds16(h3p + (size_t)idx*128 + chs*8, (char*)Al + cc*16);
        }
        __syncthreads();
        f32x4 acc[2][4];
        #pragma unroll
        for (int m=0;m<2;m++)
            #pragma unroll
            for (int n=0;n<4;n++) acc[m][n] = (f32x4){0.f,0.f,0.f,0.f};
        kd_mfma(Al, Bl, wm, wn, l15, lhi, acc);
        #pragma unroll
        for (int m=0;m<2;m++)
            #pragma unroll
            for (int r=0;r<4;r++){
                int p = wm*32 + m*16 + lhi*4 + r;
                if (p < tailr){
                    #pragma unroll
                    for (int n=0;n<4;n++)
                        mx[m][n][r] = fmaxf(mx[m][n][r], acc[m][n][r]);
                }
            }
    }

    float red4[4];
    #pragma unroll
    for (int n=0;n<4;n++){
        float v = -3.0e38f;
        #pragma unroll
        for (int m=0;m<2;m++)
            #pragma unroll
            for (int r=0;r<4;r++) v = fmaxf(v, mx[m][n][r]);
        v = fmaxf(v, __shfl_xor(v, 16));
        v = fmaxf(v, __shfl_xor(v, 32));
        red4[n] = v;
    }
    if (lhi == 0){
        #pragma unroll
        for (int n=0;n<4;n++) red[wm][wn][n*16 + l15] = red4[n];
    }
    __syncthreads();
    if (wm == 0){
        float v = fmaxf(red[0][wn][lane], red[1][wn][lane]);
        int col = n0 + wn*64 + lane;
        v = fmaxf(v + pilW4b[(size_t)sb*768 + col], 0.f);
        out[(size_t)sb*768 + col] = v;
    }
}

// ---- kE: per-pillar BatchNorm over (B, 768), in place ----
__global__ __launch_bounds__(256) void kE(float* __restrict__ out,
                                          const float* __restrict__ gamma,
                                          const float* __restrict__ beta){
    int p = blockIdx.x;
    int tid = threadIdx.x;
    float v[B_*3];
    float sum = 0.f, ssq = 0.f;
    #pragma unroll
    for (int b=0;b<B_;b++)
        #pragma unroll
        for (int r=0;r<3;r++){
            float t = out[(b*NPIL + p)*768 + tid + r*256];
            v[b*3+r] = t;
            sum += t; ssq += t*t;
        }
    #pragma unroll
    for (int off=32; off; off>>=1){
        sum += __shfl_xor(sum, off);
        ssq += __shfl_xor(ssq, off);
    }
    __shared__ float ls[8];
    __shared__ float sc[2];
    int lane = tid & 63, w = tid >> 6;
    if (lane == 0){ ls[w] = sum; ls[4+w] = ssq; }
    __syncthreads();
    if (tid == 0){
        float S = ls[0]+ls[1]+ls[2]+ls[3];
        float Q = ls[4]+ls[5]+ls[6]+ls[7];
        float mean = S * (1.0f/6144.0f);
        float var  = Q * (1.0f/6144.0f) - mean*mean;
        float scale = rsqrtf(var + BN_EPS) * gamma[p];
        sc[0] = scale;
        sc[1] = beta[p] - mean*scale;
    }
    __syncthreads();
    float scale = sc[0], shift = sc[1];
    #pragma unroll
    for (int b=0;b<B_;b++)
        #pragma unroll
        for (int r=0;r<3;r++)
            out[(b*NPIL + p)*768 + tid + r*256] = v[b*3+r]*scale + shift;
}

extern "C" void kernel_launch(void* const* d_in, const int* in_sizes, int n_in,
                              void* d_out, int out_size, void* d_ws, size_t ws_size,
                              hipStream_t stream){
    if (ws_size < (size_t)WS_NEED) return;
    const float* x     = (const float*)d_in[0];
    const float* W1    = (const float*)d_in[1];
    const float* W2    = (const float*)d_in[2];
    const float* W3    = (const float*)d_in[3];
    const float* W4    = (const float*)d_in[4];
    const float* gamma = (const float*)d_in[5];
    const float* beta  = (const float*)d_in[6];
    float* out = (float*)d_out;
    char*  ws  = (char*)d_ws;

    int*            counts = (int*)           (ws + OFF_COUNTS);
    float*          sums   = (float*)         (ws + OFF_SUMS);
    int*            starts = (int*)           (ws + OFF_STARTS);
    float*          cent   = (float*)         (ws + OFF_CENT);
    int*            segrank= (int*)           (ws + OFF_SEG);
    unsigned short* W3bf   = (unsigned short*)(ws + OFF_W3BF);
    unsigned short* W4T    = (unsigned short*)(ws + OFF_W4T);
    unsigned short* pilbf  = (unsigned short*)(ws + OFF_PILBF);
    float*          pilW4b = (float*)         (ws + OFF_PILW4B);
    unsigned short* h3p    = (unsigned short*)(ws + OFF_H3P);

    hipMemsetAsync(d_ws, 0, ZERO_BYTES, stream);

    kA<<<256, 256, 0, stream>>>(x, segrank, counts, sums);
    kScan<<<1, 1024, 0, stream>>>(counts, starts);
    kB<<<(2400+8192+196608+255)/256, 256, 0, stream>>>(counts, sums, cent, W3, W3bf, W4, W4T);
    kC12<<<(NPTS+255)/256, 256, 0, stream>>>(x, segrank, starts, cent, W1, W2, h3p);
    kC3<<<NPTS/256, 512, 0, stream>>>(W3bf, h3p);
    kM<<<NSB, 256, 0, stream>>>(h3p, starts, pilbf);
    dim3 gPB((NSB+127)/128, 6);
    kPB<<<gPB, 256, 0, stream>>>(pilbf, W4T, pilW4b);
    kD<<<4800, 256, 0, stream>>>(h3p, starts, pilW4b, W4T, out);
    kE<<<NPIL, 256, 0, stream>>>(out, gamma, beta);
}

// Round 20
// 162.654 us; speedup vs baseline: 1.2385x; 1.0101x over previous
//
#include <hip/hip_runtime.h>
#include <stdint.h>

#define B_    8
#define N_    20000
#define NPTS  (B_*N_)        // 160000
#define G_    10
#define NPIL  100
#define NSB   (B_*NPIL)      // 800 segments
#define BN_EPS 1e-5f

// ---- workspace layout (bytes) ----
#define OFF_COUNTS   0            // 800*4 = 3200
#define OFF_SUMS     3200         // 2400*4 = 9600
#define OFF_STARTS   12800        // 801*4
#define ZERO_BYTES   16320
#define OFF_CENT     19264        // 2400*4
#define OFF_SEG      28864        // 160000*4 (packed seg | rank<<10)
#define OFF_W3BF     668864       // 128*64*2 bf16 [col][k]
#define OFF_W4T      709824       // 768*256*2 bf16 [col][k]
#define OFF_PILBF    1103040      // 800*128*2 bf16
#define OFF_PILW4B   1307840      // 800*768*4 fp32
#define OFF_H3P      3765440      // 160000*128*2 bf16, SORTED rows (upper half hosts h2 temporarily)
#define WS_NEED      44725440

typedef __attribute__((ext_vector_type(8))) short bf16x8;
typedef __attribute__((ext_vector_type(4))) float f32x4;

typedef const __attribute__((address_space(1))) void gas_void;
typedef __attribute__((address_space(3))) void las_void;

__device__ __forceinline__ void gload_lds16(const void* g, void* l){
    __builtin_amdgcn_global_load_lds((gas_void*)g, (las_void*)l, 16, 0, 0);
}

__device__ __forceinline__ int binidx(float v){
    float t = v + 1.0f;
    t = fminf(fmaxf(t, 0.0f), 1.99f);
    return (int)(t / 0.2f);
}
__device__ __forceinline__ unsigned short f2bf(float f){
    unsigned u = __float_as_uint(f);
    u += 0x7fffu + ((u >> 16) & 1u);
    return (unsigned short)(u >> 16);
}
__device__ __forceinline__ unsigned u16max2(unsigned a, unsigned b){
    unsigned ah=a>>16, bh=b>>16, al=a&0xffffu, bl=b&0xffffu;
    return ((ah>bh?ah:bh)<<16) | (al>bl?al:bl);
}
__device__ __forceinline__ uint4 max16(uint4 a, uint4 b){
    uint4 r; r.x=u16max2(a.x,b.x); r.y=u16max2(a.y,b.y);
    r.z=u16max2(a.z,b.z); r.w=u16max2(a.w,b.w); return r;
}

// shared MFMA chunk body for kD (64 rows x 128 cols, K=128, &15 swizzle)
__device__ __forceinline__ void kd_mfma(const unsigned short* Al, const unsigned short* Bl,
                                        int wm, int wn, int l15, int lhi, f32x4 acc[2][4]){
    #pragma unroll
    for (int kk=0; kk<4; kk++){
        bf16x8 af[2], bfr[4];
        #pragma unroll
        for (int f=0; f<2; f++){
            int ra = wm*32 + f*16 + l15;
            af[f]  = *(const bf16x8*)((const char*)Al + ra*256 + (((kk*4+lhi) ^ (ra&15))*16));
        }
        #pragma unroll
        for (int f=0; f<4; f++){
            int rb = wn*64 + f*16 + l15;
            bfr[f] = *(const bf16x8*)((const char*)Bl + rb*256 + (((kk*4+lhi) ^ (rb&15))*16));
        }
        #pragma unroll
        for (int m=0;m<2;m++)
            #pragma unroll
            for (int n=0;n<4;n++)
                acc[m][n] = __builtin_amdgcn_mfma_f32_16x16x32_bf16(af[m], bfr[n], acc[m][n], 0,0,0);
    }
}

// ---- kA: blocks 0..255 = per-batch histogram (pillar id + rank, LDS-aggregated);
//      blocks 256..1055 = W3/W4 transposes (independent work, overlapped) ----
__global__ __launch_bounds__(256) void kA(const float* __restrict__ x,
                                          int* __restrict__ segrank,
                                          int* __restrict__ counts,
                                          float* __restrict__ sums,
                                          const float* __restrict__ W3,
                                          unsigned short* __restrict__ W3bf,
                                          const float* __restrict__ W4,
                                          unsigned short* __restrict__ W4T){
    int blk = blockIdx.x;
    int tid = threadIdx.x;
    if (blk >= 256){
        int idx = (blk-256)*256 + tid;        // 0..204799
        if (idx < 8192){
            int col = idx >> 6, k = idx & 63; // W3[k][col] -> W3bf[col][k]
            W3bf[idx] = f2bf(W3[k*128 + col]);
        } else {
            int t = idx - 8192;               // t = k*768 + j (coalesced read)
            int k = t / 768, j = t - k*768;
            W4T[j*256 + k] = f2bf(W4[t]);
        }
        return;
    }
    __shared__ int   lc[NPIL];
    __shared__ float lsum[NPIL*3];
    __shared__ int   lbase[NPIL];
    if (tid < NPIL){
        lc[tid] = 0;
        lsum[3*tid] = 0.f; lsum[3*tid+1] = 0.f; lsum[3*tid+2] = 0.f;
    }
    __syncthreads();
    int i0  = blk * 625;
    int bat = i0 / N_;                        // uniform within block
    int sv[3], lrv[3];
    #pragma unroll
    for (int t = 0; t < 3; t++){
        int ii = tid + t*256;
        int i  = i0 + ii;
        sv[t] = -1;
        if (ii < 625){
            float x0 = x[3*i], x1 = x[3*i+1], x2 = x[3*i+2];
            int s = binidx(x0)*G_ + binidx(x2);
            sv[t] = s;
            lrv[t] = atomicAdd(&lc[s], 1);
            atomicAdd(&lsum[s*3+0], x1);
            atomicAdd(&lsum[s*3+1], x0);
            atomicAdd(&lsum[s*3+2], x2);
        }
    }
    __syncthreads();
    if (tid < NPIL){
        int c = lc[tid];
        if (c > 0){
            int sb = bat*NPIL + tid;
            lbase[tid] = atomicAdd(&counts[sb], c);
            atomicAdd(&sums[3*sb+0], lsum[3*tid+0]);
            atomicAdd(&sums[3*sb+1], lsum[3*tid+1]);
            atomicAdd(&sums[3*sb+2], lsum[3*tid+2]);
        }
    }
    __syncthreads();
    #pragma unroll
    for (int t = 0; t < 3; t++){
        if (sv[t] >= 0){
            int i = i0 + tid + t*256;
            segrank[i] = (bat*NPIL + sv[t]) | ((lbase[sv[t]] + lrv[t]) << 10);
        }
    }
}

// ---- kScan: exclusive prefix sum over 800 counts + centroids (1 block) ----
__global__ __launch_bounds__(1024) void kScan(const int* __restrict__ counts,
                                              const float* __restrict__ sums,
                                              int* __restrict__ starts,
                                              float* __restrict__ cent){
    __shared__ int s[1024];
    int t = threadIdx.x;
    int c = (t < NSB) ? counts[t] : 0;
    s[t] = c;
    __syncthreads();
    for (int off=1; off<1024; off<<=1){
        int v = (t >= off) ? s[t-off] : 0;
        __syncthreads();
        s[t] += v;
        __syncthreads();
    }
    if (t < NSB) starts[t] = s[t]-c;
    if (t == NSB) starts[NSB] = s[NSB-1];
    for (int idx = t; idx < 2400; idx += 1024)
        cent[idx] = sums[idx] / fmaxf((float)counts[idx/3], 1.0f);
}

// ---- kC12: per-point layers 1+2 (fp32 VALU), h2 -> bf16 into UPPER half of h3p row ----
__global__ __launch_bounds__(256) void kC12(const float* __restrict__ x,
                                            const int* __restrict__ segrank,
                                            const int* __restrict__ starts,
                                            const float* __restrict__ cent,
                                            const float* __restrict__ W1,
                                            const float* __restrict__ W2,
                                            unsigned short* __restrict__ h3p){
    int i = blockIdx.x*256 + threadIdx.x;
    if (i >= NPTS) return;
    int pk = segrank[i];
    int sb = pk & 1023;
    int pos = starts[sb] + (pk >> 10);
    float p0 = x[3*i+1], p1 = x[3*i], p2 = x[3*i+2];
    float aug[6];
    aug[0]=p0; aug[1]=p1; aug[2]=p2;
    aug[3]=p0-cent[sb*3+0]; aug[4]=p1-cent[sb*3+1]; aug[5]=p2-cent[sb*3+2];

    float h1[32];
    #pragma unroll
    for (int j=0;j<32;j++){
        float a = 0.f;
        #pragma unroll
        for (int k=0;k<6;k++) a += aug[k]*W1[k*32+j];
        h1[j] = fmaxf(a, 0.f);
    }
    unsigned buf[32];
    #pragma unroll 8
    for (int jp=0;jp<32;jp++){
        float a0 = 0.f, a1 = 0.f;
        #pragma unroll
        for (int k=0;k<32;k++){
            a0 += h1[k]*W2[k*64 + jp*2];
            a1 += h1[k]*W2[k*64 + jp*2 + 1];
        }
        buf[jp] = (unsigned)f2bf(fmaxf(a0,0.f)) | ((unsigned)f2bf(fmaxf(a1,0.f)) << 16);
    }
    uint4* d4 = (uint4*)(h3p + (size_t)pos*128 + 64);
    #pragma unroll
    for (int q=0;q<8;q++) d4[q] = ((const uint4*)buf)[q];
}

// ---- kC3: MFMA GEMM h3[160000,128] = relu(h2[160000,64] @ W3), in place ----
__global__ __launch_bounds__(512) void kC3(const unsigned short* __restrict__ W3bf,
                                           unsigned short* __restrict__ h3p){
    __shared__ unsigned short Al[256*64];
    __shared__ unsigned short Bl[128*64];
    int tid = threadIdx.x;
    int m0  = blockIdx.x * 256;
    #pragma unroll
    for (int it=0; it<4; it++){
        int cc = tid + it*512;
        int row = cc >> 3, ch = cc & 7;
        int chs = ch ^ (row & 7);
        gload_lds16(h3p + (size_t)(m0+row)*128 + 64 + chs*8, (char*)Al + cc*16);
    }
    #pragma unroll
    for (int it=0; it<2; it++){
        int cc = tid + it*512;
        int row = cc >> 3, ch = cc & 7;
        int chs = ch ^ (row & 7);
        gload_lds16(W3bf + (size_t)row*64 + chs*8, (char*)Bl + cc*16);
    }
    __syncthreads();

    int lane = tid & 63, wid = tid >> 6;
    int wm = wid >> 1, wn = wid & 1;
    int l15 = lane & 15, lhi = lane >> 4;

    f32x4 acc[4][4];
    #pragma unroll
    for (int m=0;m<4;m++)
        #pragma unroll
        for (int n=0;n<4;n++) acc[m][n] = (f32x4){0.f,0.f,0.f,0.f};

    #pragma unroll
    for (int kk=0; kk<2; kk++){
        bf16x8 af[4], bfr[4];
        #pragma unroll
        for (int f=0; f<4; f++){
            int ra = wm*64 + f*16 + l15;
            af[f]  = *(const bf16x8*)((char*)Al + ra*128 + (((kk*4+lhi) ^ (ra&7))*16));
            int rb = wn*64 + f*16 + l15;
            bfr[f] = *(const bf16x8*)((char*)Bl + rb*128 + (((kk*4+lhi) ^ (rb&7))*16));
        }
        #pragma unroll
        for (int m=0;m<4;m++)
            #pragma unroll
            for (int n=0;n<4;n++)
                acc[m][n] = __builtin_amdgcn_mfma_f32_16x16x32_bf16(af[m], bfr[n], acc[m][n], 0,0,0);
    }

    #pragma unroll
    for (int m=0;m<4;m++)
        #pragma unroll
        for (int r=0;r<4;r++){
            int row = m0 + wm*64 + m*16 + lhi*4 + r;
            #pragma unroll
            for (int n=0;n<4;n++){
                int col = wn*64 + n*16 + l15;
                h3p[(size_t)row*128 + col] = f2bf(fmaxf(acc[m][n][r], 0.f));
            }
        }
}

// ---- kM: per-pillar segment-max of h3 (wide loads, LDS tree) ----
__global__ __launch_bounds__(256) void kM(const unsigned short* __restrict__ h3p,
                                          const int* __restrict__ starts,
                                          unsigned short* __restrict__ pilbf){
    __shared__ uint4 sd[16][16];
    int sb = blockIdx.x;
    int tx = threadIdx.x & 15, ty = threadIdx.x >> 4;
    int s = starts[sb], npts = starts[sb+1] - s;
    uint4 acc = {0u,0u,0u,0u};
    for (int p = ty; p < npts; p += 16){
        uint4 v = *(const uint4*)(h3p + (size_t)(s+p)*128 + tx*8);
        acc = max16(acc, v);
    }
    sd[ty][tx] = acc;
    __syncthreads();
    #pragma unroll
    for (int off=8; off; off>>=1){
        if (ty < off) sd[ty][tx] = max16(sd[ty][tx], sd[ty+off][tx]);
        __syncthreads();
    }
    if (ty == 0) *(uint4*)(pilbf + sb*128 + tx*8) = sd[0][tx];
}

// ---- kPB: MFMA GEMM pilW4b[800,768] = pilbf[800,128] @ W4[128:,:] ----
__global__ __launch_bounds__(256) void kPB(const unsigned short* __restrict__ pilbf,
                                           const unsigned short* __restrict__ W4T,
                                           float* __restrict__ pilW4b){
    __shared__ unsigned short Al[128*128];
    __shared__ unsigned short Bl[128*128];
    int m0 = blockIdx.x * 128;
    int n0 = blockIdx.y * 128;
    int tid = threadIdx.x;
    #pragma unroll
    for (int it=0; it<8; it++){
        int cc = tid + it*256;
        int row = cc >> 4, ch = cc & 15;
        int chs = ch ^ (row & 15);
        uint4 v = {0u,0u,0u,0u};
        if (m0 + row < NSB) v = *(const uint4*)(pilbf + (size_t)(m0+row)*128 + chs*8);
        *(uint4*)((char*)Al + cc*16) = v;
        uint4 vb = *(const uint4*)(W4T + (size_t)(n0+row)*256 + 128 + chs*8);
        *(uint4*)((char*)Bl + cc*16) = vb;
    }
    __syncthreads();
    int lane = tid & 63, wid = tid >> 6;
    int wm = wid >> 1, wn = wid & 1;
    int l15 = lane & 15, lhi = lane >> 4;
    f32x4 acc[4][4];
    #pragma unroll
    for (int m=0;m<4;m++)
        #pragma unroll
        for (int n=0;n<4;n++) acc[m][n] = (f32x4){0.f,0.f,0.f,0.f};
    #pragma unroll
    for (int kk=0; kk<4; kk++){
        bf16x8 af[4], bfr[4];
        #pragma unroll
        for (int f=0; f<4; f++){
            int ra = wm*64 + f*16 + l15;
            af[f]  = *(const bf16x8*)((char*)Al + ra*256 + (((kk*4+lhi) ^ (ra&15))*16));
            int rb = wn*64 + f*16 + l15;
            bfr[f] = *(const bf16x8*)((char*)Bl + rb*256 + (((kk*4+lhi) ^ (rb&15))*16));
        }
        #pragma unroll
        for (int m=0;m<4;m++)
            #pragma unroll
            for (int n=0;n<4;n++)
                acc[m][n] = __builtin_amdgcn_mfma_f32_16x16x32_bf16(af[m], bfr[n], acc[m][n], 0,0,0);
    }
    #pragma unroll
    for (int m=0;m<4;m++)
        #pragma unroll
        for (int r=0;r<4;r++){
            int p = wm*64 + m*16 + lhi*4 + r;
            int sbp = m0 + p;
            if (sbp < NSB){
                #pragma unroll
                for (int n=0;n<4;n++)
                    pilW4b[(size_t)sbp*768 + n0 + wn*64 + n*16 + l15] = acc[m][n][r];
            }
        }
}

// ---- kD: R13/R19 version (best measured). XCD-paired (sb,nt); async gload_lds;
//      64-row chunks; peeled full/tail; deferred bias+relu at final write ----
__global__ __launch_bounds__(256) void kD(const unsigned short* __restrict__ h3p,
                                          const int* __restrict__ starts,
                                          const float* __restrict__ pilW4b,
                                          const unsigned short* __restrict__ W4T,
                                          float* __restrict__ out){
    __shared__ unsigned short Al[64*128];    // 16KB
    __shared__ unsigned short Bl[128*128];   // 32KB
    __shared__ float red[2][2][64];
    int b  = blockIdx.x;
    int x_ = b & 7, t_ = b >> 3;
    int k_ = t_ / 6, nt = t_ - k_*6;
    int sb = x_ + 8*k_;
    int n0 = nt * 128;
    int tid = threadIdx.x;
    int start = starts[sb];
    int npts  = starts[sb+1] - start;
    if (npts == 0){
        if (tid < 128) out[(size_t)sb*768 + n0 + tid] = 0.f;
        return;
    }
    // stage B async (in flight until first barrier)
    #pragma unroll
    for (int it=0; it<8; it++){
        int cc = tid + it*256;
        int row = cc >> 4, ch = cc & 15;
        int chs = ch ^ (row & 15);
        gload_lds16(W4T + (size_t)(n0+row)*256 + chs*8, (char*)Bl + cc*16);
    }
    // hoisted per-thread A-stage source pointers (advance 64 rows = 16KB per chunk)
    const unsigned short* asrc[4];
    int arow[4];
    #pragma unroll
    for (int it=0; it<4; it++){
        int cc = tid + it*256;
        int row = cc >> 4, ch = cc & 15;
        int chs = ch ^ (row & 15);
        arow[it] = row;
        asrc[it] = h3p + (size_t)(start+row)*128 + chs*8;
    }
    int lane = tid & 63, wid = tid >> 6;
    int wm = wid >> 1, wn = wid & 1;
    int l15 = lane & 15, lhi = lane >> 4;

    float mx[2][4][4];
    #pragma unroll
    for (int m=0;m<2;m++)
        #pragma unroll
        for (int n=0;n<4;n++)
            #pragma unroll
            for (int r=0;r<4;r++) mx[m][n][r] = -3.0e38f;

    int nfull = npts >> 6;
    int tailr = npts - (nfull << 6);

    for (int c=0; c<nfull; c++){
        __syncthreads();
        #pragma unroll
        for (int it=0; it<4; it++){
            gload_lds16(asrc[it], (char*)Al + (tid + it*256)*16);
            asrc[it] += 64*128;
        }
        __syncthreads();
        f32x4 acc[2][4];
        #pragma unroll
        for (int m=0;m<2;m++)
            #pragma unroll
            for (int n=0;n<4;n++) acc[m][n] = (f32x4){0.f,0.f,0.f,0.f};
        kd_mfma(Al, Bl, wm, wn, l15, lhi, acc);
        #pragma unroll
        for (int m=0;m<2;m++)
            #pragma unroll
            for (int n=0;n<4;n++)
                #pragma unroll
                for (int r=0;r<4;r++)
                    mx[m][n][r] = fmaxf(mx[m][n][r], acc[m][n][r]);
    }
    if (tailr > 0){
        int base = nfull << 6;
        __syncthreads();
        #pragma unroll
        for (int it=0; it<4; it++){
            // rows >= npts read neighbor data (in-bounds via clamp); excluded by predicate
            int idx = start + base + arow[it];
            idx = idx < NPTS ? idx : NPTS-1;
            int cc = tid + it*256;
            int chs = (cc & 15) ^ (arow[it] & 15);
            gload_lds16(h3p + (size_t)idx*128 + chs*8, (char*)Al + cc*16);
        }
        __syncthreads();
        f32x4 acc[2][4];
        #pragma unroll
        for (int m=0;m<2;m++)
            #pragma unroll
            for (int n=0;n<4;n++) acc[m][n] = (f32x4){0.f,0.f,0.f,0.f};
        kd_mfma(Al, Bl, wm, wn, l15, lhi, acc);
        #pragma unroll
        for (int m=0;m<2;m++)
            #pragma unroll
            for (int r=0;r<4;r++){
                int p = wm*32 + m*16 + lhi*4 + r;
                if (p < tailr){
                    #pragma unroll
                    for (int n=0;n<4;n++)
                        mx[m][n][r] = fmaxf(mx[m][n][r], acc[m][n][r]);
                }
            }
    }

    float red4[4];
    #pragma unroll
    for (int n=0;n<4;n++){
        float v = -3.0e38f;
        #pragma unroll
        for (int m=0;m<2;m++)
            #pragma unroll
            for (int r=0;r<4;r++) v = fmaxf(v, mx[m][n][r]);
        v = fmaxf(v, __shfl_xor(v, 16));
        v = fmaxf(v, __shfl_xor(v, 32));
        red4[n] = v;
    }
    if (lhi == 0){
        #pragma unroll
        for (int n=0;n<4;n++) red[wm][wn][n*16 + l15] = red4[n];
    }
    __syncthreads();
    if (wm == 0){
        float v = fmaxf(red[0][wn][lane], red[1][wn][lane]);
        int col = n0 + wn*64 + lane;
        v = fmaxf(v + pilW4b[(size_t)sb*768 + col], 0.f);
        out[(size_t)sb*768 + col] = v;
    }
}

// ---- kE: per-pillar BatchNorm over (B, 768), in place ----
__global__ __launch_bounds__(256) void kE(float* __restrict__ out,
                                          const float* __restrict__ gamma,
                                          const float* __restrict__ beta){
    int p = blockIdx.x;
    int tid = threadIdx.x;
    float v[B_*3];
    float sum = 0.f, ssq = 0.f;
    #pragma unroll
    for (int b=0;b<B_;b++)
        #pragma unroll
        for (int r=0;r<3;r++){
            float t = out[(b*NPIL + p)*768 + tid + r*256];
            v[b*3+r] = t;
            sum += t; ssq += t*t;
        }
    #pragma unroll
    for (int off=32; off; off>>=1){
        sum += __shfl_xor(sum, off);
        ssq += __shfl_xor(ssq, off);
    }
    __shared__ float ls[8];
    __shared__ float sc[2];
    int lane = tid & 63, w = tid >> 6;
    if (lane == 0){ ls[w] = sum; ls[4+w] = ssq; }
    __syncthreads();
    if (tid == 0){
        float S = ls[0]+ls[1]+ls[2]+ls[3];
        float Q = ls[4]+ls[5]+ls[6]+ls[7];
        float mean = S * (1.0f/6144.0f);
        float var  = Q * (1.0f/6144.0f) - mean*mean;
        float scale = rsqrtf(var + BN_EPS) * gamma[p];
        sc[0] = scale;
        sc[1] = beta[p] - mean*scale;
    }
    __syncthreads();
    float scale = sc[0], shift = sc[1];
    #pragma unroll
    for (int b=0;b<B_;b++)
        #pragma unroll
        for (int r=0;r<3;r++)
            out[(b*NPIL + p)*768 + tid + r*256] = v[b*3+r]*scale + shift;
}

extern "C" void kernel_launch(void* const* d_in, const int* in_sizes, int n_in,
                              void* d_out, int out_size, void* d_ws, size_t ws_size,
                              hipStream_t stream){
    if (ws_size < (size_t)WS_NEED) return;
    const float* x     = (const float*)d_in[0];
    const float* W1    = (const float*)d_in[1];
    const float* W2    = (const float*)d_in[2];
    const float* W3    = (const float*)d_in[3];
    const float* W4    = (const float*)d_in[4];
    const float* gamma = (const float*)d_in[5];
    const float* beta  = (const float*)d_in[6];
    float* out = (float*)d_out;
    char*  ws  = (char*)d_ws;

    int*            counts = (int*)           (ws + OFF_COUNTS);
    float*          sums   = (float*)         (ws + OFF_SUMS);
    int*            starts = (int*)           (ws + OFF_STARTS);
    float*          cent   = (float*)         (ws + OFF_CENT);
    int*            segrank= (int*)           (ws + OFF_SEG);
    unsigned short* W3bf   = (unsigned short*)(ws + OFF_W3BF);
    unsigned short* W4T    = (unsigned short*)(ws + OFF_W4T);
    unsigned short* pilbf  = (unsigned short*)(ws + OFF_PILBF);
    float*          pilW4b = (float*)         (ws + OFF_PILW4B);
    unsigned short* h3p    = (unsigned short*)(ws + OFF_H3P);

    hipMemsetAsync(d_ws, 0, ZERO_BYTES, stream);

    kA<<<1056, 256, 0, stream>>>(x, segrank, counts, sums, W3, W3bf, W4, W4T);
    kScan<<<1, 1024, 0, stream>>>(counts, sums, starts, cent);
    kC12<<<(NPTS+255)/256, 256, 0, stream>>>(x, segrank, starts, cent, W1, W2, h3p);
    kC3<<<NPTS/256, 512, 0, stream>>>(W3bf, h3p);
    kM<<<NSB, 256, 0, stream>>>(h3p, starts, pilbf);
    dim3 gPB((NSB+127)/128, 6);
    kPB<<<gPB, 256, 0, stream>>>(pilbf, W4T, pilW4b);
    kD<<<4800, 256, 0, stream>>>(h3p, starts, pilW4b, W4T, out);
    kE<<<NPIL, 256, 0, stream>>>(out, gamma, beta);
}